// Round 3
// baseline (4487.360 us; speedup 1.0000x reference)
//
#include <hip/hip_runtime.h>
#include <math.h>

#define E 256
#define NTOK 1024
#define NB 32
#define NLAYER 12
#define LN_EPS 1e-5f

typedef __attribute__((ext_vector_type(8))) short bf16x8;
typedef __attribute__((ext_vector_type(4))) float f32x4;
#define MFMA16(a, b, c) __builtin_amdgcn_mfma_f32_16x16x32_bf16(a, b, c, 0, 0, 0)

__device__ __forceinline__ ushort f2bf(float f) {
    union { float f; unsigned u; } v; v.f = f;
    return (ushort)((v.u + 0x7fffu + ((v.u >> 16) & 1u)) >> 16);
}

// ---------------------------------------------------------------- weight prep
// One block per [256][256] matrix: emit WT[n][k] bf16 (B-fragment-friendly).
__global__ __launch_bounds__(256) void k_wprep(
    const float* __restrict__ Wq, const float* __restrict__ Wk, const float* __restrict__ Wv,
    const float* __restrict__ W1, const float* __restrict__ W2,
    ushort* __restrict__ WT)
{
    const int mat = blockIdx.x % 5;
    const int l   = blockIdx.x / 5;
    const float* src = (mat == 0 ? Wq : mat == 1 ? Wk : mat == 2 ? Wv : mat == 3 ? W1 : W2)
                       + (size_t)l * E * E;
    ushort* dst = WT + ((size_t)(l * 5 + mat) << 16);
    const int n = threadIdx.x;                       // output row
    #pragma unroll
    for (int c = 0; c < 4; ++c) {                    // k chunks of 64
        #pragma unroll
        for (int j = 0; j < 8; ++j) {                // 8 k's per store
            const int k0 = c * 64 + j * 8;
            float v0 = src[(size_t)(k0 + 0) * E + n];
            float v1 = src[(size_t)(k0 + 1) * E + n];
            float v2 = src[(size_t)(k0 + 2) * E + n];
            float v3 = src[(size_t)(k0 + 3) * E + n];
            float v4 = src[(size_t)(k0 + 4) * E + n];
            float v5 = src[(size_t)(k0 + 5) * E + n];
            float v6 = src[(size_t)(k0 + 6) * E + n];
            float v7 = src[(size_t)(k0 + 7) * E + n];
            uint4 u;
            u.x = (uint)f2bf(v0) | ((uint)f2bf(v1) << 16);
            u.y = (uint)f2bf(v2) | ((uint)f2bf(v3) << 16);
            u.z = (uint)f2bf(v4) | ((uint)f2bf(v5) << 16);
            u.w = (uint)f2bf(v6) | ((uint)f2bf(v7) << 16);
            *(uint4*)&dst[(size_t)n * E + k0] = u;
        }
    }
}

// ---------------------------------------------------------------- embed
__global__ __launch_bounds__(256) void k_embed(
    const float* __restrict__ xs, const float* __restrict__ ys,
    const float* __restrict__ W_in, const float* __restrict__ b_in,
    float* __restrict__ H, ushort* __restrict__ Hb)
{
    __shared__ float zs[16][64];
    const int tid = threadIdx.x;
    const int r0 = blockIdx.x * 16;
    #pragma unroll
    for (int l = 0; l < 4; ++l) {
        int lin = tid + l * 256;
        int i = lin >> 6, d = lin & 63;
        int row = r0 + i;
        int t = row & (NTOK - 1);
        float v;
        if (d < 63) v = xs[(size_t)row * 63 + d];
        else        v = (t == NTOK - 1) ? 0.f : ys[row];
        zs[i][d] = v;
    }
    __syncthreads();
    float acc[16];
    #pragma unroll
    for (int i = 0; i < 16; ++i) acc[i] = 0.f;
    for (int d = 0; d < 64; ++d) {
        float w = W_in[d * E + tid];
        #pragma unroll
        for (int i = 0; i < 16; ++i) acc[i] = fmaf(zs[i][d], w, acc[i]);
    }
    float bb = b_in[tid];
    #pragma unroll
    for (int i = 0; i < 16; ++i) {
        float o = acc[i] + bb;
        H [(size_t)(r0 + i) * E + tid] = o;
        Hb[(size_t)(r0 + i) * E + tid] = f2bf(o);
    }
}

// ---------------------------------------------------------------- MFMA qkv
// 64 token-rows/block, 4 waves. A-frags register-resident. Q,K normal
// orientation (LDS-linearized coalesced store); V with swapped operands so
// the output lands directly in VT[e][tok] layout.
__global__ __launch_bounds__(256, 2) void k_qkv(
    const ushort* __restrict__ Hb,
    const ushort* __restrict__ WqT, const ushort* __restrict__ WkT, const ushort* __restrict__ WvT,
    ushort* __restrict__ Qb, ushort* __restrict__ Kb, ushort* __restrict__ VTg)
{
    __shared__ __align__(16) ushort Hs[64][264];
    const int tid = threadIdx.x;
    const int w = tid >> 6, l = tid & 63;
    const int lr = l & 15, lg = l >> 4;
    const size_t r0 = (size_t)blockIdx.x * 64;
    const int b    = (int)(r0 >> 10);
    const int tok0 = (int)(r0 & (NTOK - 1));

    #pragma unroll
    for (int it = 0; it < 8; ++it) {
        int idx = it * 256 + tid;
        int row = idx >> 5, ch = idx & 31;
        bf16x8 v = *(const bf16x8*)&Hb[(r0 + row) * E + ch * 8];
        *(bf16x8*)&Hs[row][ch * 8] = v;
    }
    __syncthreads();

    bf16x8 a[8];
    #pragma unroll
    for (int kk = 0; kk < 8; ++kk)
        a[kk] = *(const bf16x8*)&Hs[w * 16 + lr][kk * 32 + lg * 8];

    // ---- V pass (swapped): C[e_out][tok] = WvT-row x H-row
    {
        f32x4 vacc[4][4];
        #pragma unroll
        for (int mt = 0; mt < 4; ++mt)
            #pragma unroll
            for (int nt = 0; nt < 4; ++nt) vacc[mt][nt] = (f32x4){0.f, 0.f, 0.f, 0.f};
        for (int kk = 0; kk < 8; ++kk) {
            bf16x8 av[4], bh[4];
            #pragma unroll
            for (int mt = 0; mt < 4; ++mt)
                av[mt] = *(const bf16x8*)&WvT[(size_t)(w * 64 + mt * 16 + lr) * E + kk * 32 + lg * 8];
            #pragma unroll
            for (int nt = 0; nt < 4; ++nt)
                bh[nt] = *(const bf16x8*)&Hs[nt * 16 + lr][kk * 32 + lg * 8];
            #pragma unroll
            for (int mt = 0; mt < 4; ++mt)
                #pragma unroll
                for (int nt = 0; nt < 4; ++nt)
                    vacc[mt][nt] = MFMA16(av[mt], bh[nt], vacc[mt][nt]);
        }
        #pragma unroll
        for (int mt = 0; mt < 4; ++mt)
            #pragma unroll
            for (int nt = 0; nt < 4; ++nt)
                #pragma unroll
                for (int r = 0; r < 4; ++r)
                    VTg[((size_t)b * E + w * 64 + mt * 16 + lg * 4 + r) * NTOK + tok0 + nt * 16 + lr]
                        = f2bf(vacc[mt][nt][r]);
    }
    __syncthreads();   // all waves done reading Hs; safe to reuse as out-staging

    // ---- Q then K (normal orientation)
    #pragma unroll 1
    for (int pass = 0; pass < 2; ++pass) {
        const ushort* Wt = pass ? WkT : WqT;
        ushort* Out = pass ? Kb : Qb;
        f32x4 acc[16];
        #pragma unroll
        for (int nt = 0; nt < 16; ++nt) acc[nt] = (f32x4){0.f, 0.f, 0.f, 0.f};
        for (int kk = 0; kk < 8; ++kk) {
            #pragma unroll
            for (int nt = 0; nt < 16; ++nt) {
                bf16x8 bw = *(const bf16x8*)&Wt[(size_t)(nt * 16 + lr) * E + kk * 32 + lg * 8];
                acc[nt] = MFMA16(a[kk], bw, acc[nt]);
            }
        }
        #pragma unroll
        for (int nt = 0; nt < 16; ++nt)
            #pragma unroll
            for (int r = 0; r < 4; ++r)
                Hs[w * 16 + lg * 4 + r][nt * 16 + lr] = f2bf(acc[nt][r]);
        // wave-private rows -> in-wave ordering; coalesced copy-out
        #pragma unroll
        for (int j = 0; j < 8; ++j) {
            int idx = j * 64 + l;
            int rowl = idx >> 5, ch = idx & 31;
            bf16x8 v = *(const bf16x8*)&Hs[w * 16 + rowl][ch * 8];
            *(bf16x8*)&Out[(r0 + w * 16 + rowl) * E + ch * 8] = v;
        }
    }
}

// ---------------------------------------------------------------- MFMA attention + residual + LN1
__global__ __launch_bounds__(256, 2) void k_attn(
    const ushort* __restrict__ Qb, const ushort* __restrict__ Kb, const ushort* __restrict__ VTg,
    float* __restrict__ H, ushort* __restrict__ HbO,
    const float* __restrict__ g1, const float* __restrict__ be1)
{
    __shared__ __align__(16) ushort Ks[32][264];
    __shared__ __align__(16) ushort VT[256][32];
    __shared__ __align__(16) ushort Pl[4][16][40];
    const int tid = threadIdx.x;
    const int w  = tid >> 6, l = tid & 63;
    const int lr = l & 15, lg = l >> 4;

    const int wq  = blockIdx.x;
    const int p   = wq >> 3;
    const int batch = ((wq & 7) << 2) | (p & 3);
    const int qt  = p >> 2;

    const size_t kvbase = (size_t)batch * NTOK * E;
    const size_t vtbase = (size_t)batch * E * NTOK;
    const int    qrow0  = qt * 64 + w * 16;
    const size_t qbase  = kvbase + (size_t)qrow0 * E;

    bf16x8 qf[8];
    #pragma unroll
    for (int kk = 0; kk < 8; ++kk)
        qf[kk] = *(const bf16x8*)&Qb[qbase + (size_t)lr * E + kk * 32 + lg * 8];

    f32x4 o[16];
    #pragma unroll
    for (int nt = 0; nt < 16; ++nt) o[nt] = (f32x4){0.f, 0.f, 0.f, 0.f};

    const int skrow = tid >> 3;
    const int se0   = (tid & 7) * 32;
    const float inv_n = 1.0f / (float)NTOK;

    for (int jt = 0; jt < 32; ++jt) {
        const int k0 = jt * 32;
        __syncthreads();
        #pragma unroll
        for (int c = 0; c < 4; ++c) {
            bf16x8 kv = *(const bf16x8*)&Kb[kvbase + (size_t)(k0 + skrow) * E + se0 + c * 8];
            *(bf16x8*)&Ks[skrow][se0 + c * 8] = kv;
        }
        #pragma unroll
        for (int c = 0; c < 4; ++c) {
            bf16x8 vv = *(const bf16x8*)&VTg[vtbase + (size_t)tid * NTOK + k0 + c * 8];
            *(bf16x8*)&VT[tid][c * 8] = vv;
        }
        __syncthreads();

        f32x4 s0 = (f32x4){0.f, 0.f, 0.f, 0.f};
        f32x4 s1 = (f32x4){0.f, 0.f, 0.f, 0.f};
        #pragma unroll
        for (int kk = 0; kk < 8; ++kk) {
            bf16x8 b0 = *(const bf16x8*)&Ks[lr][kk * 32 + lg * 8];
            bf16x8 b1 = *(const bf16x8*)&Ks[16 + lr][kk * 32 + lg * 8];
            s0 = MFMA16(qf[kk], b0, s0);
            s1 = MFMA16(qf[kk], b1, s1);
        }
        #pragma unroll
        for (int r = 0; r < 4; ++r) {
            Pl[w][lg * 4 + r][lr]      = f2bf(fmaxf(s0[r], 0.f) * inv_n);
            Pl[w][lg * 4 + r][16 + lr] = f2bf(fmaxf(s1[r], 0.f) * inv_n);
        }
        bf16x8 pa = *(const bf16x8*)&Pl[w][lr][lg * 8];
        #pragma unroll
        for (int nt = 0; nt < 16; ++nt) {
            bf16x8 vb = *(const bf16x8*)&VT[nt * 16 + lr][lg * 8];
            o[nt] = MFMA16(pa, vb, o[nt]);
        }
    }

    float gg[16], bb[16];
    #pragma unroll
    for (int nt = 0; nt < 16; ++nt) {
        gg[nt] = g1[nt * 16 + lr];
        bb[nt] = be1[nt * 16 + lr];
    }
    #pragma unroll
    for (int r = 0; r < 4; ++r) {
        const int q = lg * 4 + r;
        const size_t rowbase = kvbase + (size_t)(qrow0 + q) * E;
        float xv[16];
        float s = 0.f, s2 = 0.f;
        #pragma unroll
        for (int nt = 0; nt < 16; ++nt) {
            float val = H[rowbase + nt * 16 + lr] + o[nt][r];
            xv[nt] = val;
            s += val; s2 += val * val;
        }
        #pragma unroll
        for (int m = 1; m < 16; m <<= 1) {
            s  += __shfl_xor(s, m, 64);
            s2 += __shfl_xor(s2, m, 64);
        }
        float mu = s * (1.f / 256.f);
        float rs = rsqrtf(s2 * (1.f / 256.f) - mu * mu + LN_EPS);
        #pragma unroll
        for (int nt = 0; nt < 16; ++nt) {
            float ov = (xv[nt] - mu) * rs * gg[nt] + bb[nt];
            H  [rowbase + nt * 16 + lr] = ov;
            HbO[rowbase + nt * 16 + lr] = f2bf(ov);
        }
    }
}

// ---------------------------------------------------------------- MFMA MLP + residual + LN2
__global__ __launch_bounds__(256, 2) void k_mlp(
    const ushort* __restrict__ Hb, float* __restrict__ H, ushort* __restrict__ HbO,
    const ushort* __restrict__ W1T, const float* __restrict__ b1,
    const ushort* __restrict__ W2T, const float* __restrict__ b2,
    const float* __restrict__ g2, const float* __restrict__ be2)
{
    __shared__ __align__(16) ushort Hs[64][264];
    const int tid = threadIdx.x;
    const int w = tid >> 6, l = tid & 63;
    const int lr = l & 15, lg = l >> 4;
    const size_t r0 = (size_t)blockIdx.x * 64;

    #pragma unroll
    for (int it = 0; it < 8; ++it) {
        int idx = it * 256 + tid;
        int row = idx >> 5, ch = idx & 31;
        bf16x8 v = *(const bf16x8*)&Hb[(r0 + row) * E + ch * 8];
        *(bf16x8*)&Hs[row][ch * 8] = v;
    }
    __syncthreads();

    bf16x8 a1[8];
    #pragma unroll
    for (int kk = 0; kk < 8; ++kk)
        a1[kk] = *(const bf16x8*)&Hs[w * 16 + lr][kk * 32 + lg * 8];
    __syncthreads();   // everyone done with Hs; wave-private T region reuse

    f32x4 acc[16];
    #pragma unroll
    for (int nt = 0; nt < 16; ++nt) acc[nt] = (f32x4){0.f, 0.f, 0.f, 0.f};
    for (int kk = 0; kk < 8; ++kk) {
        #pragma unroll
        for (int nt = 0; nt < 16; ++nt) {
            bf16x8 bw = *(const bf16x8*)&W1T[(size_t)(nt * 16 + lr) * E + kk * 32 + lg * 8];
            acc[nt] = MFMA16(a1[kk], bw, acc[nt]);
        }
    }
    #pragma unroll
    for (int nt = 0; nt < 16; ++nt) {
        float bv = b1[nt * 16 + lr];
        #pragma unroll
        for (int r = 0; r < 4; ++r)
            Hs[w * 16 + lg * 4 + r][nt * 16 + lr] = f2bf(fmaxf(acc[nt][r] + bv, 0.f));
    }
    bf16x8 a2[8];
    #pragma unroll
    for (int kk = 0; kk < 8; ++kk)
        a2[kk] = *(const bf16x8*)&Hs[w * 16 + lr][kk * 32 + lg * 8];

    f32x4 acc2[16];
    #pragma unroll
    for (int nt = 0; nt < 16; ++nt) acc2[nt] = (f32x4){0.f, 0.f, 0.f, 0.f};
    for (int kk = 0; kk < 8; ++kk) {
        #pragma unroll
        for (int nt = 0; nt < 16; ++nt) {
            bf16x8 bw = *(const bf16x8*)&W2T[(size_t)(nt * 16 + lr) * E + kk * 32 + lg * 8];
            acc2[nt] = MFMA16(a2[kk], bw, acc2[nt]);
        }
    }

    float gg[16], bb[16], b2v[16];
    #pragma unroll
    for (int nt = 0; nt < 16; ++nt) {
        gg[nt]  = g2[nt * 16 + lr];
        bb[nt]  = be2[nt * 16 + lr];
        b2v[nt] = b2[nt * 16 + lr];
    }
    #pragma unroll
    for (int r = 0; r < 4; ++r) {
        const size_t rowbase = (r0 + w * 16 + lg * 4 + r) * E;
        float xv[16];
        float s = 0.f, s2 = 0.f;
        #pragma unroll
        for (int nt = 0; nt < 16; ++nt) {
            float val = H[rowbase + nt * 16 + lr] + acc2[nt][r] + b2v[nt];
            xv[nt] = val;
            s += val; s2 += val * val;
        }
        #pragma unroll
        for (int m = 1; m < 16; m <<= 1) {
            s  += __shfl_xor(s, m, 64);
            s2 += __shfl_xor(s2, m, 64);
        }
        float mu = s * (1.f / 256.f);
        float rs = rsqrtf(s2 * (1.f / 256.f) - mu * mu + LN_EPS);
        #pragma unroll
        for (int nt = 0; nt < 16; ++nt) {
            float ov = (xv[nt] - mu) * rs * gg[nt] + bb[nt];
            H  [rowbase + nt * 16 + lr] = ov;
            HbO[rowbase + nt * 16 + lr] = f2bf(ov);
        }
    }
}

// ---------------------------------------------------------------- readout
__global__ __launch_bounds__(256) void k_readout(
    const float* __restrict__ H, const float* __restrict__ W_out,
    const float* __restrict__ b_out, float* __restrict__ out)
{
    const int tid = threadIdx.x;
    const int lane = tid & 63;
    const int row = blockIdx.x * 4 + (tid >> 6);
    float s = 0.f;
    #pragma unroll
    for (int j = 0; j < 4; ++j)
        s += H[(size_t)row * E + j * 64 + lane] * W_out[j * 64 + lane];
    #pragma unroll
    for (int m = 1; m < 64; m <<= 1) s += __shfl_xor(s, m, 64);
    if (lane == 0) out[row] = s + b_out[0];
}

// ----------------------------------------------------------------
extern "C" void kernel_launch(void* const* d_in, const int* in_sizes, int n_in,
                              void* d_out, int out_size, void* d_ws, size_t ws_size,
                              hipStream_t stream)
{
    const float* xs    = (const float*)d_in[0];
    const float* ys    = (const float*)d_in[1];
    const float* W_in  = (const float*)d_in[2];
    const float* b_in  = (const float*)d_in[3];
    const float* Wq    = (const float*)d_in[4];
    const float* Wk    = (const float*)d_in[5];
    const float* Wv    = (const float*)d_in[6];
    const float* g1    = (const float*)d_in[7];
    const float* be1   = (const float*)d_in[8];
    const float* W1    = (const float*)d_in[9];
    const float* b1    = (const float*)d_in[10];
    const float* W2    = (const float*)d_in[11];
    const float* b2    = (const float*)d_in[12];
    const float* g2    = (const float*)d_in[13];
    const float* be2   = (const float*)d_in[14];
    const float* W_out = (const float*)d_in[15];
    const float* b_out = (const float*)d_in[16];
    (void)in_sizes; (void)n_in; (void)out_size; (void)ws_size;

    const size_t SZ = (size_t)NB * NTOK * E;        // 8,388,608 elements
    float*  H   = (float*)d_ws;                     // 33.5 MB fp32
    ushort* Hb  = (ushort*)(H + SZ);                // 16.8 MB bf16 shadow
    ushort* Qb  = Hb + SZ;
    ushort* Kb  = Qb + SZ;
    ushort* VTg = Kb + SZ;                          // [b][e][tok]
    ushort* WT  = VTg + SZ;                         // 12*5*65536 bf16 transposed weights

    k_wprep<<<dim3(NLAYER * 5), dim3(256), 0, stream>>>(Wq, Wk, Wv, W1, W2, WT);
    k_embed<<<dim3(2048), dim3(256), 0, stream>>>(xs, ys, W_in, b_in, H, Hb);
    for (int i = 0; i < NLAYER; ++i) {
        const size_t vo = (size_t)i * E;
        const ushort* WqT = WT + ((size_t)(i * 5 + 0) << 16);
        const ushort* WkT = WT + ((size_t)(i * 5 + 1) << 16);
        const ushort* WvT = WT + ((size_t)(i * 5 + 2) << 16);
        const ushort* W1T = WT + ((size_t)(i * 5 + 3) << 16);
        const ushort* W2T = WT + ((size_t)(i * 5 + 4) << 16);
        k_qkv<<<dim3(512), dim3(256), 0, stream>>>(Hb, WqT, WkT, WvT, Qb, Kb, VTg);
        k_attn<<<dim3(512), dim3(256), 0, stream>>>(Qb, Kb, VTg, H, Hb, g1 + vo, be1 + vo);
        k_mlp<<<dim3(512), dim3(256), 0, stream>>>(Hb, H, Hb, W1T, b1 + vo, W2T, b2 + vo,
                                                   g2 + vo, be2 + vo);
    }
    k_readout<<<dim3((NB * NTOK) / 4), dim3(256), 0, stream>>>(H, W_out, b_out, (float*)d_out);
}

// Round 5
// 3118.237 us; speedup vs baseline: 1.4391x; 1.4391x over previous
//
#include <hip/hip_runtime.h>
#include <math.h>

#define E 256
#define NTOK 1024
#define NB 32
#define NLAYER 12
#define LN_EPS 1e-5f

typedef __attribute__((ext_vector_type(8))) short bf16x8;
typedef __attribute__((ext_vector_type(4))) float f32x4;
#define MFMA16(a, b, c) __builtin_amdgcn_mfma_f32_16x16x32_bf16(a, b, c, 0, 0, 0)

__device__ __forceinline__ ushort f2bf(float f) {
    union { float f; unsigned u; } v; v.f = f;
    return (ushort)((v.u + 0x7fffu + ((v.u >> 16) & 1u)) >> 16);
}

// ---------------------------------------------------------------- weight prep
// WT[n][k] = W[k][n], bf16. One block per matrix.
__global__ __launch_bounds__(256) void k_wprep(
    const float* __restrict__ Wq, const float* __restrict__ Wk, const float* __restrict__ Wv,
    const float* __restrict__ W1, const float* __restrict__ W2,
    ushort* __restrict__ WT)
{
    const int mat = blockIdx.x % 5;
    const int l   = blockIdx.x / 5;
    const float* src = (mat == 0 ? Wq : mat == 1 ? Wk : mat == 2 ? Wv : mat == 3 ? W1 : W2)
                       + (size_t)l * E * E;
    ushort* dst = WT + ((size_t)(l * 5 + mat) << 16);
    const int n = threadIdx.x;
    #pragma unroll
    for (int c = 0; c < 4; ++c) {
        #pragma unroll
        for (int j = 0; j < 8; ++j) {
            const int k0 = c * 64 + j * 8;
            uint4 u;
            u.x = (uint)f2bf(src[(size_t)(k0 + 0) * E + n]) | ((uint)f2bf(src[(size_t)(k0 + 1) * E + n]) << 16);
            u.y = (uint)f2bf(src[(size_t)(k0 + 2) * E + n]) | ((uint)f2bf(src[(size_t)(k0 + 3) * E + n]) << 16);
            u.z = (uint)f2bf(src[(size_t)(k0 + 4) * E + n]) | ((uint)f2bf(src[(size_t)(k0 + 5) * E + n]) << 16);
            u.w = (uint)f2bf(src[(size_t)(k0 + 6) * E + n]) | ((uint)f2bf(src[(size_t)(k0 + 7) * E + n]) << 16);
            *(uint4*)&dst[(size_t)n * E + k0] = u;
        }
    }
}

// ---------------------------------------------------------------- embed
__global__ __launch_bounds__(256) void k_embed(
    const float* __restrict__ xs, const float* __restrict__ ys,
    const float* __restrict__ W_in, const float* __restrict__ b_in,
    float* __restrict__ H, ushort* __restrict__ Hb)
{
    __shared__ float zs[16][64];
    const int tid = threadIdx.x;
    const int r0 = blockIdx.x * 16;
    #pragma unroll
    for (int l = 0; l < 4; ++l) {
        int lin = tid + l * 256;
        int i = lin >> 6, d = lin & 63;
        int row = r0 + i;
        int t = row & (NTOK - 1);
        float v;
        if (d < 63) v = xs[(size_t)row * 63 + d];
        else        v = (t == NTOK - 1) ? 0.f : ys[row];
        zs[i][d] = v;
    }
    __syncthreads();
    float acc[16];
    #pragma unroll
    for (int i = 0; i < 16; ++i) acc[i] = 0.f;
    for (int d = 0; d < 64; ++d) {
        float w = W_in[d * E + tid];
        #pragma unroll
        for (int i = 0; i < 16; ++i) acc[i] = fmaf(zs[i][d], w, acc[i]);
    }
    float bb = b_in[tid];
    #pragma unroll
    for (int i = 0; i < 16; ++i) {
        float o = acc[i] + bb;
        H [(size_t)(r0 + i) * E + tid] = o;
        Hb[(size_t)(r0 + i) * E + tid] = f2bf(o);
    }
}

// ---------------------------------------------------------------- MFMA qkv (register-blocked)
// 64 tokens/block, 4 waves; wave w owns out-cols [w*64, +64), 4x4 fragment grid.
// B (weights) LDS-staged in BK=64 chunks; A-frags from global (L2-hot).
__global__ __launch_bounds__(256, 2) void k_qkv(
    const ushort* __restrict__ Hb,
    const ushort* __restrict__ WqT, const ushort* __restrict__ WkT, const ushort* __restrict__ WvT,
    ushort* __restrict__ Qb, ushort* __restrict__ Kb, ushort* __restrict__ VTg)
{
    __shared__ __align__(16) ushort Ws[256][72];    // 144B rows: BK=64 chunk + pad (b128 bank-floor)
    __shared__ __align__(16) ushort Sc[4][16][72];  // per-wave out-scratch
    const int tid = threadIdx.x;
    const int w = tid >> 6, l = tid & 63;
    const int lr = l & 15, lg = l >> 4;
    const size_t r0 = (size_t)blockIdx.x * 64;
    const int b    = (int)(r0 >> 10);
    const int tok0 = (int)(r0 & (NTOK - 1));
    const ushort* Wts[3] = {WqT, WkT, WvT};

    #pragma unroll 1
    for (int pass = 0; pass < 3; ++pass) {
        const ushort* Wt = Wts[pass];
        f32x4 acc[4][4];
        #pragma unroll
        for (int mt = 0; mt < 4; ++mt)
            #pragma unroll
            for (int nt = 0; nt < 4; ++nt) acc[mt][nt] = (f32x4){0.f, 0.f, 0.f, 0.f};

        #pragma unroll 1
        for (int kc = 0; kc < 4; ++kc) {
            __syncthreads();                          // prev chunk/pass compute done
            #pragma unroll
            for (int rep = 0; rep < 8; ++rep) {       // stage [256][64] chunk
                int lin = rep * 256 + tid;
                int n = lin >> 3, slot = lin & 7;
                bf16x8 v = *(const bf16x8*)&Wt[(size_t)n * E + kc * 64 + slot * 8];
                *(bf16x8*)&Ws[n][slot * 8] = v;
            }
            __syncthreads();
            #pragma unroll
            for (int kl = 0; kl < 2; ++kl) {
                bf16x8 af[4], bw[4];
                #pragma unroll
                for (int mt = 0; mt < 4; ++mt)
                    af[mt] = *(const bf16x8*)&Hb[(r0 + mt * 16 + lr) * E + kc * 64 + kl * 32 + lg * 8];
                #pragma unroll
                for (int nt = 0; nt < 4; ++nt)
                    bw[nt] = *(const bf16x8*)&Ws[w * 64 + nt * 16 + lr][kl * 32 + lg * 8];
                #pragma unroll
                for (int mt = 0; mt < 4; ++mt)
                    #pragma unroll
                    for (int nt = 0; nt < 4; ++nt)
                        acc[mt][nt] = MFMA16(af[mt], bw[nt], acc[mt][nt]);
            }
        }

        if (pass == 2) {
            // V: store transposed. Lane holds 4 consecutive toks of e-col (w*64+nt*16+lr).
            #pragma unroll
            for (int mt = 0; mt < 4; ++mt)
                #pragma unroll
                for (int nt = 0; nt < 4; ++nt) {
                    ushort4 u;
                    u.x = f2bf(acc[mt][nt][0]); u.y = f2bf(acc[mt][nt][1]);
                    u.z = f2bf(acc[mt][nt][2]); u.w = f2bf(acc[mt][nt][3]);
                    *(ushort4*)&VTg[((size_t)b * E + w * 64 + nt * 16 + lr) * NTOK
                                    + tok0 + mt * 16 + lg * 4] = u;
                }
        } else {
            ushort* Out = pass ? Kb : Qb;
            #pragma unroll 1
            for (int mt = 0; mt < 4; ++mt) {
                #pragma unroll
                for (int nt = 0; nt < 4; ++nt)
                    #pragma unroll
                    for (int r = 0; r < 4; ++r)
                        Sc[w][lg * 4 + r][nt * 16 + lr] = f2bf(acc[mt][nt][r]);
                // same-wave RAW via LDS (compiler inserts lgkmcnt)
                #pragma unroll
                for (int j = 0; j < 2; ++j) {
                    bf16x8 v = *(const bf16x8*)&Sc[w][l >> 2][(l & 3) * 16 + j * 8];
                    *(bf16x8*)&Out[(r0 + mt * 16 + (l >> 2)) * E + w * 64 + (l & 3) * 16 + j * 8] = v;
                }
            }
        }
    }
}

// ---------------------------------------------------------------- MFMA attention + residual + LN1
__global__ __launch_bounds__(256, 2) void k_attn(
    const ushort* __restrict__ Qb, const ushort* __restrict__ Kb, const ushort* __restrict__ VTg,
    float* __restrict__ H, ushort* __restrict__ HbO,
    const float* __restrict__ g1, const float* __restrict__ be1)
{
    __shared__ __align__(16) ushort Ks[32][264];
    __shared__ __align__(16) ushort VT[256][32];    // slot-swizzled (see below)
    __shared__ __align__(16) ushort Pl[4][16][40];
    const int tid = threadIdx.x;
    const int w  = tid >> 6, l = tid & 63;
    const int lr = l & 15, lg = l >> 4;

    const int wq  = blockIdx.x;
    const int p   = wq >> 3;
    const int batch = ((wq & 7) << 2) | (p & 3);
    const int qt  = p >> 2;

    const size_t kvbase = (size_t)batch * NTOK * E;
    const size_t vtbase = (size_t)batch * E * NTOK;
    const int    qrow0  = qt * 64 + w * 16;
    const size_t qbase  = kvbase + (size_t)qrow0 * E;

    bf16x8 qf[8];
    #pragma unroll
    for (int kk = 0; kk < 8; ++kk)
        qf[kk] = *(const bf16x8*)&Qb[qbase + (size_t)lr * E + kk * 32 + lg * 8];

    f32x4 o[16];
    #pragma unroll
    for (int nt = 0; nt < 16; ++nt) o[nt] = (f32x4){0.f, 0.f, 0.f, 0.f};

    const int skrow = tid >> 3;
    const int se0   = (tid & 7) * 32;
    const int vslotx = (tid >> 1) & 3;              // write-side slot swizzle
    const int rslotx = (lr >> 1) & 3;               // read-side slot swizzle
    const float inv_n = 1.0f / (float)NTOK;

    for (int jt = 0; jt < 32; ++jt) {
        const int k0 = jt * 32;
        __syncthreads();
        #pragma unroll
        for (int c = 0; c < 4; ++c) {
            bf16x8 kv = *(const bf16x8*)&Kb[kvbase + (size_t)(k0 + skrow) * E + se0 + c * 8];
            *(bf16x8*)&Ks[skrow][se0 + c * 8] = kv;
        }
        #pragma unroll
        for (int c = 0; c < 4; ++c) {
            bf16x8 vv = *(const bf16x8*)&VTg[vtbase + (size_t)tid * NTOK + k0 + c * 8];
            *(bf16x8*)&VT[tid][(c ^ vslotx) * 8] = vv;
        }
        __syncthreads();

        f32x4 s0 = (f32x4){0.f, 0.f, 0.f, 0.f};
        f32x4 s1 = (f32x4){0.f, 0.f, 0.f, 0.f};
        #pragma unroll
        for (int kk = 0; kk < 8; ++kk) {
            bf16x8 b0 = *(const bf16x8*)&Ks[lr][kk * 32 + lg * 8];
            bf16x8 b1 = *(const bf16x8*)&Ks[16 + lr][kk * 32 + lg * 8];
            s0 = MFMA16(qf[kk], b0, s0);
            s1 = MFMA16(qf[kk], b1, s1);
        }
        #pragma unroll
        for (int r = 0; r < 4; ++r) {
            Pl[w][lg * 4 + r][lr]      = f2bf(fmaxf(s0[r], 0.f) * inv_n);
            Pl[w][lg * 4 + r][16 + lr] = f2bf(fmaxf(s1[r], 0.f) * inv_n);
        }
        bf16x8 pa = *(const bf16x8*)&Pl[w][lr][lg * 8];
        #pragma unroll
        for (int nt = 0; nt < 16; ++nt) {
            bf16x8 vb = *(const bf16x8*)&VT[nt * 16 + lr][(lg ^ rslotx) * 8];
            o[nt] = MFMA16(pa, vb, o[nt]);
        }
    }

    float gg[16], bb[16];
    #pragma unroll
    for (int nt = 0; nt < 16; ++nt) {
        gg[nt] = g1[nt * 16 + lr];
        bb[nt] = be1[nt * 16 + lr];
    }
    #pragma unroll
    for (int r = 0; r < 4; ++r) {
        const int q = lg * 4 + r;
        const size_t rowbase = kvbase + (size_t)(qrow0 + q) * E;
        float xv[16];
        float s = 0.f, s2 = 0.f;
        #pragma unroll
        for (int nt = 0; nt < 16; ++nt) {
            float val = H[rowbase + nt * 16 + lr] + o[nt][r];
            xv[nt] = val;
            s += val; s2 += val * val;
        }
        #pragma unroll
        for (int m = 1; m < 16; m <<= 1) {
            s  += __shfl_xor(s, m, 64);
            s2 += __shfl_xor(s2, m, 64);
        }
        float mu = s * (1.f / 256.f);
        float rs = rsqrtf(s2 * (1.f / 256.f) - mu * mu + LN_EPS);
        #pragma unroll
        for (int nt = 0; nt < 16; ++nt) {
            float ov = (xv[nt] - mu) * rs * gg[nt] + bb[nt];
            H  [rowbase + nt * 16 + lr] = ov;
            HbO[rowbase + nt * 16 + lr] = f2bf(ov);
        }
    }
}

// ---------------------------------------------------------------- MFMA MLP (register-blocked) + residual + LN2
// 64 tokens/block, 4 waves; wave w owns out-cols [w*64,+64).
__global__ __launch_bounds__(256, 2) void k_mlp(
    const ushort* __restrict__ Hb, float* __restrict__ H, ushort* __restrict__ HbO,
    const ushort* __restrict__ W1T, const float* __restrict__ b1,
    const ushort* __restrict__ W2T, const float* __restrict__ b2,
    const float* __restrict__ g2, const float* __restrict__ be2)
{
    __shared__ __align__(16) ushort Ws[256][72];    // 144B rows: BK=64 chunk + pad
    __shared__ __align__(16) ushort Ts[64][264];    // 528B rows
    __shared__ float part[4][64][2];
    __shared__ float stats[64][2];
    const int tid = threadIdx.x;
    const int w = tid >> 6, l = tid & 63;
    const int lr = l & 15, lg = l >> 4;
    const size_t r0 = (size_t)blockIdx.x * 64;

    // ---- GEMM1: T = relu(H @ W1 + b1)
    f32x4 acc[4][4];
    #pragma unroll
    for (int mt = 0; mt < 4; ++mt)
        #pragma unroll
        for (int nt = 0; nt < 4; ++nt) acc[mt][nt] = (f32x4){0.f, 0.f, 0.f, 0.f};
    #pragma unroll 1
    for (int kc = 0; kc < 4; ++kc) {
        __syncthreads();
        #pragma unroll
        for (int rep = 0; rep < 8; ++rep) {
            int lin = rep * 256 + tid;
            int n = lin >> 3, slot = lin & 7;
            bf16x8 v = *(const bf16x8*)&W1T[(size_t)n * E + kc * 64 + slot * 8];
            *(bf16x8*)&Ws[n][slot * 8] = v;
        }
        __syncthreads();
        #pragma unroll
        for (int kl = 0; kl < 2; ++kl) {
            bf16x8 af[4], bw[4];
            #pragma unroll
            for (int mt = 0; mt < 4; ++mt)
                af[mt] = *(const bf16x8*)&Hb[(r0 + mt * 16 + lr) * E + kc * 64 + kl * 32 + lg * 8];
            #pragma unroll
            for (int nt = 0; nt < 4; ++nt)
                bw[nt] = *(const bf16x8*)&Ws[w * 64 + nt * 16 + lr][kl * 32 + lg * 8];
            #pragma unroll
            for (int mt = 0; mt < 4; ++mt)
                #pragma unroll
                for (int nt = 0; nt < 4; ++nt)
                    acc[mt][nt] = MFMA16(af[mt], bw[nt], acc[mt][nt]);
        }
    }
    {
        float bb1[4];
        #pragma unroll
        for (int nt = 0; nt < 4; ++nt) bb1[nt] = b1[w * 64 + nt * 16 + lr];
        #pragma unroll
        for (int mt = 0; mt < 4; ++mt)
            #pragma unroll
            for (int nt = 0; nt < 4; ++nt)
                #pragma unroll
                for (int r = 0; r < 4; ++r)
                    Ts[mt * 16 + lg * 4 + r][w * 64 + nt * 16 + lr]
                        = f2bf(fmaxf(acc[mt][nt][r] + bb1[nt], 0.f));
    }

    // ---- GEMM2: out = T @ W2   (Ts write->read ordered by kc=0 barrier)
    f32x4 acc2[4][4];
    #pragma unroll
    for (int mt = 0; mt < 4; ++mt)
        #pragma unroll
        for (int nt = 0; nt < 4; ++nt) acc2[mt][nt] = (f32x4){0.f, 0.f, 0.f, 0.f};
    #pragma unroll 1
    for (int kc = 0; kc < 4; ++kc) {
        __syncthreads();
        #pragma unroll
        for (int rep = 0; rep < 8; ++rep) {
            int lin = rep * 256 + tid;
            int n = lin >> 3, slot = lin & 7;
            bf16x8 v = *(const bf16x8*)&W2T[(size_t)n * E + kc * 64 + slot * 8];
            *(bf16x8*)&Ws[n][slot * 8] = v;
        }
        __syncthreads();
        #pragma unroll
        for (int kl = 0; kl < 2; ++kl) {
            bf16x8 af[4], bw[4];
            #pragma unroll
            for (int mt = 0; mt < 4; ++mt)
                af[mt] = *(const bf16x8*)&Ts[mt * 16 + lr][kc * 64 + kl * 32 + lg * 8];
            #pragma unroll
            for (int nt = 0; nt < 4; ++nt)
                bw[nt] = *(const bf16x8*)&Ws[w * 64 + nt * 16 + lr][kl * 32 + lg * 8];
            #pragma unroll
            for (int mt = 0; mt < 4; ++mt)
                #pragma unroll
                for (int nt = 0; nt < 4; ++nt)
                    acc2[mt][nt] = MFMA16(af[mt], bw[nt], acc2[mt][nt]);
        }
    }

    // ---- residual + LN2 (cross-wave row reduction)
    {
        float b2v[4];
        #pragma unroll
        for (int nt = 0; nt < 4; ++nt) b2v[nt] = b2[w * 64 + nt * 16 + lr];
        #pragma unroll
        for (int mt = 0; mt < 4; ++mt)
            #pragma unroll
            for (int r = 0; r < 4; ++r)
                #pragma unroll
                for (int nt = 0; nt < 4; ++nt)
                    acc2[mt][nt][r] += H[(r0 + mt * 16 + lg * 4 + r) * E + w * 64 + nt * 16 + lr]
                                       + b2v[nt];
    }
    #pragma unroll
    for (int mt = 0; mt < 4; ++mt)
        #pragma unroll
        for (int r = 0; r < 4; ++r) {
            float s = 0.f, s2 = 0.f;
            #pragma unroll
            for (int nt = 0; nt < 4; ++nt) {
                float v = acc2[mt][nt][r];
                s += v; s2 += v * v;
            }
            #pragma unroll
            for (int m = 1; m < 16; m <<= 1) {
                s  += __shfl_xor(s, m, 64);
                s2 += __shfl_xor(s2, m, 64);
            }
            if (lr == 0) {
                part[w][mt * 16 + lg * 4 + r][0] = s;
                part[w][mt * 16 + lg * 4 + r][1] = s2;
            }
        }
    __syncthreads();
    if (tid < 64) {
        float s = part[0][tid][0] + part[1][tid][0] + part[2][tid][0] + part[3][tid][0];
        float s2 = part[0][tid][1] + part[1][tid][1] + part[2][tid][1] + part[3][tid][1];
        float mu = s * (1.f / 256.f);
        stats[tid][0] = mu;
        stats[tid][1] = rsqrtf(s2 * (1.f / 256.f) - mu * mu + LN_EPS);
    }
    __syncthreads();
    {
        float gg[4], be[4];
        #pragma unroll
        for (int nt = 0; nt < 4; ++nt) {
            gg[nt] = g2[w * 64 + nt * 16 + lr];
            be[nt] = be2[w * 64 + nt * 16 + lr];
        }
        #pragma unroll
        for (int mt = 0; mt < 4; ++mt)
            #pragma unroll
            for (int r = 0; r < 4; ++r) {
                const int row = mt * 16 + lg * 4 + r;
                const float mu = stats[row][0], rs = stats[row][1];
                const size_t rowbase = (r0 + row) * E;
                #pragma unroll
                for (int nt = 0; nt < 4; ++nt) {
                    float ov = (acc2[mt][nt][r] - mu) * rs * gg[nt] + be[nt];
                    H  [rowbase + w * 64 + nt * 16 + lr] = ov;
                    HbO[rowbase + w * 64 + nt * 16 + lr] = f2bf(ov);
                }
            }
    }
}

// ---------------------------------------------------------------- readout
__global__ __launch_bounds__(256) void k_readout(
    const float* __restrict__ H, const float* __restrict__ W_out,
    const float* __restrict__ b_out, float* __restrict__ out)
{
    const int tid = threadIdx.x;
    const int lane = tid & 63;
    const int row = blockIdx.x * 4 + (tid >> 6);
    float s = 0.f;
    #pragma unroll
    for (int j = 0; j < 4; ++j)
        s += H[(size_t)row * E + j * 64 + lane] * W_out[j * 64 + lane];
    #pragma unroll
    for (int m = 1; m < 64; m <<= 1) s += __shfl_xor(s, m, 64);
    if (lane == 0) out[row] = s + b_out[0];
}

// ----------------------------------------------------------------
extern "C" void kernel_launch(void* const* d_in, const int* in_sizes, int n_in,
                              void* d_out, int out_size, void* d_ws, size_t ws_size,
                              hipStream_t stream)
{
    const float* xs    = (const float*)d_in[0];
    const float* ys    = (const float*)d_in[1];
    const float* W_in  = (const float*)d_in[2];
    const float* b_in  = (const float*)d_in[3];
    const float* Wq    = (const float*)d_in[4];
    const float* Wk    = (const float*)d_in[5];
    const float* Wv    = (const float*)d_in[6];
    const float* g1    = (const float*)d_in[7];
    const float* be1   = (const float*)d_in[8];
    const float* W1    = (const float*)d_in[9];
    const float* b1    = (const float*)d_in[10];
    const float* W2    = (const float*)d_in[11];
    const float* b2    = (const float*)d_in[12];
    const float* g2    = (const float*)d_in[13];
    const float* be2   = (const float*)d_in[14];
    const float* W_out = (const float*)d_in[15];
    const float* b_out = (const float*)d_in[16];
    (void)in_sizes; (void)n_in; (void)out_size; (void)ws_size;

    const size_t SZ = (size_t)NB * NTOK * E;
    float*  H   = (float*)d_ws;
    ushort* Hb  = (ushort*)(H + SZ);
    ushort* Qb  = Hb + SZ;
    ushort* Kb  = Qb + SZ;
    ushort* VTg = Kb + SZ;                          // [b][e][tok]
    ushort* WT  = VTg + SZ;                         // 60 x 64K bf16 transposed weights

    k_wprep<<<dim3(NLAYER * 5), dim3(256), 0, stream>>>(Wq, Wk, Wv, W1, W2, WT);
    k_embed<<<dim3(2048), dim3(256), 0, stream>>>(xs, ys, W_in, b_in, H, Hb);
    for (int i = 0; i < NLAYER; ++i) {
        const size_t vo = (size_t)i * E;
        const ushort* WqT = WT + ((size_t)(i * 5 + 0) << 16);
        const ushort* WkT = WT + ((size_t)(i * 5 + 1) << 16);
        const ushort* WvT = WT + ((size_t)(i * 5 + 2) << 16);
        const ushort* W1T = WT + ((size_t)(i * 5 + 3) << 16);
        const ushort* W2T = WT + ((size_t)(i * 5 + 4) << 16);
        k_qkv<<<dim3(512), dim3(256), 0, stream>>>(Hb, WqT, WkT, WvT, Qb, Kb, VTg);
        k_attn<<<dim3(512), dim3(256), 0, stream>>>(Qb, Kb, VTg, H, Hb, g1 + vo, be1 + vo);
        k_mlp<<<dim3(512), dim3(256), 0, stream>>>(Hb, H, Hb, W1T, b1 + vo, W2T, b2 + vo,
                                                   g2 + vo, be2 + vo);
    }
    k_readout<<<dim3((NB * NTOK) / 4), dim3(256), 0, stream>>>(H, W_out, b_out, (float*)d_out);
}

// Round 6
// 2717.238 us; speedup vs baseline: 1.6514x; 1.1476x over previous
//
#include <hip/hip_runtime.h>
#include <math.h>

#define E 256
#define NTOK 1024
#define NB 32
#define NLAYER 12
#define LN_EPS 1e-5f

typedef __attribute__((ext_vector_type(8))) short bf16x8;
typedef __attribute__((ext_vector_type(4))) float f32x4;
#define MFMA16(a, b, c) __builtin_amdgcn_mfma_f32_16x16x32_bf16(a, b, c, 0, 0, 0)

__device__ __forceinline__ ushort f2bf(float f) {
    union { float f; unsigned u; } v; v.f = f;
    return (ushort)((v.u + 0x7fffu + ((v.u >> 16) & 1u)) >> 16);
}

// ---------------------------------------------------------------- weight prep
__global__ __launch_bounds__(256) void k_wprep(
    const float* __restrict__ Wq, const float* __restrict__ Wk, const float* __restrict__ Wv,
    const float* __restrict__ W1, const float* __restrict__ W2,
    ushort* __restrict__ WT)
{
    const int mat = blockIdx.x % 5;
    const int l   = blockIdx.x / 5;
    const float* src = (mat == 0 ? Wq : mat == 1 ? Wk : mat == 2 ? Wv : mat == 3 ? W1 : W2)
                       + (size_t)l * E * E;
    ushort* dst = WT + ((size_t)(l * 5 + mat) << 16);
    const int n = threadIdx.x;
    #pragma unroll
    for (int c = 0; c < 4; ++c) {
        #pragma unroll
        for (int j = 0; j < 8; ++j) {
            const int k0 = c * 64 + j * 8;
            uint4 u;
            u.x = (uint)f2bf(src[(size_t)(k0 + 0) * E + n]) | ((uint)f2bf(src[(size_t)(k0 + 1) * E + n]) << 16);
            u.y = (uint)f2bf(src[(size_t)(k0 + 2) * E + n]) | ((uint)f2bf(src[(size_t)(k0 + 3) * E + n]) << 16);
            u.z = (uint)f2bf(src[(size_t)(k0 + 4) * E + n]) | ((uint)f2bf(src[(size_t)(k0 + 5) * E + n]) << 16);
            u.w = (uint)f2bf(src[(size_t)(k0 + 6) * E + n]) | ((uint)f2bf(src[(size_t)(k0 + 7) * E + n]) << 16);
            *(uint4*)&dst[(size_t)n * E + k0] = u;
        }
    }
}

// ---------------------------------------------------------------- embed
__global__ __launch_bounds__(256) void k_embed(
    const float* __restrict__ xs, const float* __restrict__ ys,
    const float* __restrict__ W_in, const float* __restrict__ b_in,
    float* __restrict__ H, ushort* __restrict__ Hb)
{
    __shared__ float zs[16][64];
    const int tid = threadIdx.x;
    const int r0 = blockIdx.x * 16;
    #pragma unroll
    for (int l = 0; l < 4; ++l) {
        int lin = tid + l * 256;
        int i = lin >> 6, d = lin & 63;
        int row = r0 + i;
        int t = row & (NTOK - 1);
        float v;
        if (d < 63) v = xs[(size_t)row * 63 + d];
        else        v = (t == NTOK - 1) ? 0.f : ys[row];
        zs[i][d] = v;
    }
    __syncthreads();
    float acc[16];
    #pragma unroll
    for (int i = 0; i < 16; ++i) acc[i] = 0.f;
    for (int d = 0; d < 64; ++d) {
        float w = W_in[d * E + tid];
        #pragma unroll
        for (int i = 0; i < 16; ++i) acc[i] = fmaf(zs[i][d], w, acc[i]);
    }
    float bb = b_in[tid];
    #pragma unroll
    for (int i = 0; i < 16; ++i) {
        float o = acc[i] + bb;
        H [(size_t)(r0 + i) * E + tid] = o;
        Hb[(size_t)(r0 + i) * E + tid] = f2bf(o);
    }
}

// ---------------------------------------------------------------- MFMA qkv (register-blocked)
// 64 tokens/block, 4 waves; wave w owns out-cols [w*64,+64), 4x4 fragment grid.
// V output staged through Ws LDS -> row-contiguous 128B global writes (no
// sub-line write amplification).
__global__ __launch_bounds__(256, 2) void k_qkv(
    const ushort* __restrict__ Hb,
    const ushort* __restrict__ WqT, const ushort* __restrict__ WkT, const ushort* __restrict__ WvT,
    ushort* __restrict__ Qb, ushort* __restrict__ Kb, ushort* __restrict__ VTg)
{
    __shared__ __align__(16) ushort Ws[256][72];    // weights chunk; reused as V out-stage
    __shared__ __align__(16) ushort Sc[4][16][72];  // per-wave Q/K out-scratch
    const int tid = threadIdx.x;
    const int w = tid >> 6, l = tid & 63;
    const int lr = l & 15, lg = l >> 4;
    const size_t r0 = (size_t)blockIdx.x * 64;
    const int b    = (int)(r0 >> 10);
    const int tok0 = (int)(r0 & (NTOK - 1));
    const ushort* Wts[3] = {WqT, WkT, WvT};

    #pragma unroll 1
    for (int pass = 0; pass < 3; ++pass) {
        const ushort* Wt = Wts[pass];
        f32x4 acc[4][4];
        #pragma unroll
        for (int mt = 0; mt < 4; ++mt)
            #pragma unroll
            for (int nt = 0; nt < 4; ++nt) acc[mt][nt] = (f32x4){0.f, 0.f, 0.f, 0.f};

        #pragma unroll 1
        for (int kc = 0; kc < 4; ++kc) {
            __syncthreads();                          // prev chunk/pass use of Ws done
            #pragma unroll
            for (int rep = 0; rep < 8; ++rep) {       // stage [256][64] chunk
                int lin = rep * 256 + tid;
                int n = lin >> 3, slot = lin & 7;
                bf16x8 v = *(const bf16x8*)&Wt[(size_t)n * E + kc * 64 + slot * 8];
                *(bf16x8*)&Ws[n][slot * 8] = v;
            }
            __syncthreads();
            #pragma unroll
            for (int kl = 0; kl < 2; ++kl) {
                bf16x8 af[4], bw[4];
                #pragma unroll
                for (int mt = 0; mt < 4; ++mt)
                    af[mt] = *(const bf16x8*)&Hb[(r0 + mt * 16 + lr) * E + kc * 64 + kl * 32 + lg * 8];
                #pragma unroll
                for (int nt = 0; nt < 4; ++nt)
                    bw[nt] = *(const bf16x8*)&Ws[w * 64 + nt * 16 + lr][kl * 32 + lg * 8];
                #pragma unroll
                for (int mt = 0; mt < 4; ++mt)
                    #pragma unroll
                    for (int nt = 0; nt < 4; ++nt)
                        acc[mt][nt] = MFMA16(af[mt], bw[nt], acc[mt][nt]);
            }
        }

        if (pass == 2) {
            // V: stage [e][tok] tile in Ws, then coalesced copy-out
            __syncthreads();                          // all waves done reading weights
            #pragma unroll
            for (int mt = 0; mt < 4; ++mt)
                #pragma unroll
                for (int nt = 0; nt < 4; ++nt) {
                    ushort4 u;
                    u.x = f2bf(acc[mt][nt][0]); u.y = f2bf(acc[mt][nt][1]);
                    u.z = f2bf(acc[mt][nt][2]); u.w = f2bf(acc[mt][nt][3]);
                    *(ushort4*)&Ws[w * 64 + nt * 16 + lr][mt * 16 + lg * 4] = u;
                }
            __syncthreads();
            #pragma unroll
            for (int rep = 0; rep < 8; ++rep) {
                int lin = rep * 256 + tid;
                int row = lin >> 3, ch = lin & 7;    // 8 lanes = 128B contiguous per e-row
                bf16x8 v = *(const bf16x8*)&Ws[row][ch * 8];
                *(bf16x8*)&VTg[((size_t)b * E + row) * NTOK + tok0 + ch * 8] = v;
            }
        } else {
            ushort* Out = pass ? Kb : Qb;
            #pragma unroll 1
            for (int mt = 0; mt < 4; ++mt) {
                #pragma unroll
                for (int nt = 0; nt < 4; ++nt)
                    #pragma unroll
                    for (int r = 0; r < 4; ++r)
                        Sc[w][lg * 4 + r][nt * 16 + lr] = f2bf(acc[mt][nt][r]);
                // same-wave RAW via LDS (compiler inserts lgkmcnt)
                #pragma unroll
                for (int j = 0; j < 2; ++j) {
                    bf16x8 v = *(const bf16x8*)&Sc[w][l >> 2][(l & 3) * 16 + j * 8];
                    *(bf16x8*)&Out[(r0 + mt * 16 + (l >> 2)) * E + w * 64 + (l & 3) * 16 + j * 8] = v;
                }
            }
        }
    }
}

// ---------------------------------------------------------------- MFMA attention + residual + LN1
// Double-buffered K/VT staging, one barrier per K-tile. VT rows padded to 40
// ushorts (80B): row stride = 20 words mod 32 -> 8 distinct 16B positions ->
// b128 floor-optimal banks on both write and read.
__global__ __launch_bounds__(256, 2) void k_attn(
    const ushort* __restrict__ Qb, const ushort* __restrict__ Kb, const ushort* __restrict__ VTg,
    float* __restrict__ H, ushort* __restrict__ HbO,
    const float* __restrict__ g1, const float* __restrict__ be1)
{
    __shared__ __align__(16) ushort Ks[2][32][264];
    __shared__ __align__(16) ushort VT[2][256][40];
    __shared__ __align__(16) ushort Pl[4][16][40];
    const int tid = threadIdx.x;
    const int w  = tid >> 6, l = tid & 63;
    const int lr = l & 15, lg = l >> 4;

    const int wq  = blockIdx.x;
    const int p   = wq >> 3;
    const int batch = ((wq & 7) << 2) | (p & 3);    // 4 batches per XCD (KV L2-pinned)
    const int qt  = p >> 2;

    const size_t kvbase = (size_t)batch * NTOK * E;
    const size_t vtbase = (size_t)batch * E * NTOK;
    const int    qrow0  = qt * 64 + w * 16;
    const size_t qbase  = kvbase + (size_t)qrow0 * E;

    bf16x8 qf[8];
    #pragma unroll
    for (int kk = 0; kk < 8; ++kk)
        qf[kk] = *(const bf16x8*)&Qb[qbase + (size_t)lr * E + kk * 32 + lg * 8];

    f32x4 o[16];
    #pragma unroll
    for (int nt = 0; nt < 16; ++nt) o[nt] = (f32x4){0.f, 0.f, 0.f, 0.f};

    const int skrow = tid >> 3;
    const int se0   = (tid & 7) * 32;
    const float inv_n = 1.0f / (float)NTOK;

    // prologue: stage tile 0 into buffer 0
    #pragma unroll
    for (int c = 0; c < 4; ++c) {
        bf16x8 kv = *(const bf16x8*)&Kb[kvbase + (size_t)skrow * E + se0 + c * 8];
        *(bf16x8*)&Ks[0][skrow][se0 + c * 8] = kv;
    }
    #pragma unroll
    for (int c = 0; c < 4; ++c) {
        bf16x8 vv = *(const bf16x8*)&VTg[vtbase + (size_t)tid * NTOK + c * 8];
        *(bf16x8*)&VT[0][tid][c * 8] = vv;
    }
    __syncthreads();

    for (int jt = 0; jt < 32; ++jt) {
        const int cur = jt & 1;
        if (jt < 31) {                                // prefetch next tile into cur^1
            const int k0n = (jt + 1) * 32;
            #pragma unroll
            for (int c = 0; c < 4; ++c) {
                bf16x8 kv = *(const bf16x8*)&Kb[kvbase + (size_t)(k0n + skrow) * E + se0 + c * 8];
                *(bf16x8*)&Ks[cur ^ 1][skrow][se0 + c * 8] = kv;
            }
            #pragma unroll
            for (int c = 0; c < 4; ++c) {
                bf16x8 vv = *(const bf16x8*)&VTg[vtbase + (size_t)tid * NTOK + k0n + c * 8];
                *(bf16x8*)&VT[cur ^ 1][tid][c * 8] = vv;
            }
        }

        f32x4 s0 = (f32x4){0.f, 0.f, 0.f, 0.f};
        f32x4 s1 = (f32x4){0.f, 0.f, 0.f, 0.f};
        #pragma unroll
        for (int kk = 0; kk < 8; ++kk) {
            bf16x8 b0 = *(const bf16x8*)&Ks[cur][lr][kk * 32 + lg * 8];
            bf16x8 b1 = *(const bf16x8*)&Ks[cur][16 + lr][kk * 32 + lg * 8];
            s0 = MFMA16(qf[kk], b0, s0);
            s1 = MFMA16(qf[kk], b1, s1);
        }
        #pragma unroll
        for (int r = 0; r < 4; ++r) {
            Pl[w][lg * 4 + r][lr]      = f2bf(fmaxf(s0[r], 0.f) * inv_n);
            Pl[w][lg * 4 + r][16 + lr] = f2bf(fmaxf(s1[r], 0.f) * inv_n);
        }
        bf16x8 pa = *(const bf16x8*)&Pl[w][lr][lg * 8];   // same-wave RAW
        #pragma unroll
        for (int nt = 0; nt < 16; ++nt) {
            bf16x8 vb = *(const bf16x8*)&VT[cur][nt * 16 + lr][lg * 8];
            o[nt] = MFMA16(pa, vb, o[nt]);
        }
        __syncthreads();   // staging of cur^1 visible; reads of cur done
    }

    float gg[16], bb[16];
    #pragma unroll
    for (int nt = 0; nt < 16; ++nt) {
        gg[nt] = g1[nt * 16 + lr];
        bb[nt] = be1[nt * 16 + lr];
    }
    #pragma unroll
    for (int r = 0; r < 4; ++r) {
        const int q = lg * 4 + r;
        const size_t rowbase = kvbase + (size_t)(qrow0 + q) * E;
        float xv[16];
        float s = 0.f, s2 = 0.f;
        #pragma unroll
        for (int nt = 0; nt < 16; ++nt) {
            float val = H[rowbase + nt * 16 + lr] + o[nt][r];
            xv[nt] = val;
            s += val; s2 += val * val;
        }
        #pragma unroll
        for (int m = 1; m < 16; m <<= 1) {
            s  += __shfl_xor(s, m, 64);
            s2 += __shfl_xor(s2, m, 64);
        }
        float mu = s * (1.f / 256.f);
        float rs = rsqrtf(s2 * (1.f / 256.f) - mu * mu + LN_EPS);
        #pragma unroll
        for (int nt = 0; nt < 16; ++nt) {
            float ov = (xv[nt] - mu) * rs * gg[nt] + bb[nt];
            H  [rowbase + nt * 16 + lr] = ov;
            HbO[rowbase + nt * 16 + lr] = f2bf(ov);
        }
    }
}

// ---------------------------------------------------------------- MFMA MLP (register-blocked) + residual + LN2
__global__ __launch_bounds__(256, 2) void k_mlp(
    const ushort* __restrict__ Hb, float* __restrict__ H, ushort* __restrict__ HbO,
    const ushort* __restrict__ W1T, const float* __restrict__ b1,
    const ushort* __restrict__ W2T, const float* __restrict__ b2,
    const float* __restrict__ g2, const float* __restrict__ be2)
{
    __shared__ __align__(16) ushort Ws[256][72];
    __shared__ __align__(16) ushort Ts[64][264];
    __shared__ float part[4][64][2];
    __shared__ float stats[64][2];
    const int tid = threadIdx.x;
    const int w = tid >> 6, l = tid & 63;
    const int lr = l & 15, lg = l >> 4;
    const size_t r0 = (size_t)blockIdx.x * 64;

    // ---- GEMM1: T = relu(H @ W1 + b1)
    f32x4 acc[4][4];
    #pragma unroll
    for (int mt = 0; mt < 4; ++mt)
        #pragma unroll
        for (int nt = 0; nt < 4; ++nt) acc[mt][nt] = (f32x4){0.f, 0.f, 0.f, 0.f};
    #pragma unroll 1
    for (int kc = 0; kc < 4; ++kc) {
        __syncthreads();
        #pragma unroll
        for (int rep = 0; rep < 8; ++rep) {
            int lin = rep * 256 + tid;
            int n = lin >> 3, slot = lin & 7;
            bf16x8 v = *(const bf16x8*)&W1T[(size_t)n * E + kc * 64 + slot * 8];
            *(bf16x8*)&Ws[n][slot * 8] = v;
        }
        __syncthreads();
        #pragma unroll
        for (int kl = 0; kl < 2; ++kl) {
            bf16x8 af[4], bw[4];
            #pragma unroll
            for (int mt = 0; mt < 4; ++mt)
                af[mt] = *(const bf16x8*)&Hb[(r0 + mt * 16 + lr) * E + kc * 64 + kl * 32 + lg * 8];
            #pragma unroll
            for (int nt = 0; nt < 4; ++nt)
                bw[nt] = *(const bf16x8*)&Ws[w * 64 + nt * 16 + lr][kl * 32 + lg * 8];
            #pragma unroll
            for (int mt = 0; mt < 4; ++mt)
                #pragma unroll
                for (int nt = 0; nt < 4; ++nt)
                    acc[mt][nt] = MFMA16(af[mt], bw[nt], acc[mt][nt]);
        }
    }
    {
        float bb1[4];
        #pragma unroll
        for (int nt = 0; nt < 4; ++nt) bb1[nt] = b1[w * 64 + nt * 16 + lr];
        #pragma unroll
        for (int mt = 0; mt < 4; ++mt)
            #pragma unroll
            for (int nt = 0; nt < 4; ++nt)
                #pragma unroll
                for (int r = 0; r < 4; ++r)
                    Ts[mt * 16 + lg * 4 + r][w * 64 + nt * 16 + lr]
                        = f2bf(fmaxf(acc[mt][nt][r] + bb1[nt], 0.f));
    }

    // ---- GEMM2: out = T @ W2
    f32x4 acc2[4][4];
    #pragma unroll
    for (int mt = 0; mt < 4; ++mt)
        #pragma unroll
        for (int nt = 0; nt < 4; ++nt) acc2[mt][nt] = (f32x4){0.f, 0.f, 0.f, 0.f};
    #pragma unroll 1
    for (int kc = 0; kc < 4; ++kc) {
        __syncthreads();
        #pragma unroll
        for (int rep = 0; rep < 8; ++rep) {
            int lin = rep * 256 + tid;
            int n = lin >> 3, slot = lin & 7;
            bf16x8 v = *(const bf16x8*)&W2T[(size_t)n * E + kc * 64 + slot * 8];
            *(bf16x8*)&Ws[n][slot * 8] = v;
        }
        __syncthreads();
        #pragma unroll
        for (int kl = 0; kl < 2; ++kl) {
            bf16x8 af[4], bw[4];
            #pragma unroll
            for (int mt = 0; mt < 4; ++mt)
                af[mt] = *(const bf16x8*)&Ts[mt * 16 + lr][kc * 64 + kl * 32 + lg * 8];
            #pragma unroll
            for (int nt = 0; nt < 4; ++nt)
                bw[nt] = *(const bf16x8*)&Ws[w * 64 + nt * 16 + lr][kl * 32 + lg * 8];
            #pragma unroll
            for (int mt = 0; mt < 4; ++mt)
                #pragma unroll
                for (int nt = 0; nt < 4; ++nt)
                    acc2[mt][nt] = MFMA16(af[mt], bw[nt], acc2[mt][nt]);
        }
    }

    // ---- residual + LN2 (cross-wave row reduction)
    {
        float b2v[4];
        #pragma unroll
        for (int nt = 0; nt < 4; ++nt) b2v[nt] = b2[w * 64 + nt * 16 + lr];
        #pragma unroll
        for (int mt = 0; mt < 4; ++mt)
            #pragma unroll
            for (int r = 0; r < 4; ++r)
                #pragma unroll
                for (int nt = 0; nt < 4; ++nt)
                    acc2[mt][nt][r] += H[(r0 + mt * 16 + lg * 4 + r) * E + w * 64 + nt * 16 + lr]
                                       + b2v[nt];
    }
    #pragma unroll
    for (int mt = 0; mt < 4; ++mt)
        #pragma unroll
        for (int r = 0; r < 4; ++r) {
            float s = 0.f, s2 = 0.f;
            #pragma unroll
            for (int nt = 0; nt < 4; ++nt) {
                float v = acc2[mt][nt][r];
                s += v; s2 += v * v;
            }
            #pragma unroll
            for (int m = 1; m < 16; m <<= 1) {
                s  += __shfl_xor(s, m, 64);
                s2 += __shfl_xor(s2, m, 64);
            }
            if (lr == 0) {
                part[w][mt * 16 + lg * 4 + r][0] = s;
                part[w][mt * 16 + lg * 4 + r][1] = s2;
            }
        }
    __syncthreads();
    if (tid < 64) {
        float s = part[0][tid][0] + part[1][tid][0] + part[2][tid][0] + part[3][tid][0];
        float s2 = part[0][tid][1] + part[1][tid][1] + part[2][tid][1] + part[3][tid][1];
        float mu = s * (1.f / 256.f);
        stats[tid][0] = mu;
        stats[tid][1] = rsqrtf(s2 * (1.f / 256.f) - mu * mu + LN_EPS);
    }
    __syncthreads();
    {
        float gg[4], be[4];
        #pragma unroll
        for (int nt = 0; nt < 4; ++nt) {
            gg[nt] = g2[w * 64 + nt * 16 + lr];
            be[nt] = be2[w * 64 + nt * 16 + lr];
        }
        #pragma unroll
        for (int mt = 0; mt < 4; ++mt)
            #pragma unroll
            for (int r = 0; r < 4; ++r) {
                const int row = mt * 16 + lg * 4 + r;
                const float mu = stats[row][0], rs = stats[row][1];
                const size_t rowbase = (r0 + row) * E;
                #pragma unroll
                for (int nt = 0; nt < 4; ++nt) {
                    float ov = (acc2[mt][nt][r] - mu) * rs * gg[nt] + be[nt];
                    H  [rowbase + w * 64 + nt * 16 + lr] = ov;
                    HbO[rowbase + w * 64 + nt * 16 + lr] = f2bf(ov);
                }
            }
    }
}

// ---------------------------------------------------------------- readout
__global__ __launch_bounds__(256) void k_readout(
    const float* __restrict__ H, const float* __restrict__ W_out,
    const float* __restrict__ b_out, float* __restrict__ out)
{
    const int tid = threadIdx.x;
    const int lane = tid & 63;
    const int row = blockIdx.x * 4 + (tid >> 6);
    float s = 0.f;
    #pragma unroll
    for (int j = 0; j < 4; ++j)
        s += H[(size_t)row * E + j * 64 + lane] * W_out[j * 64 + lane];
    #pragma unroll
    for (int m = 1; m < 64; m <<= 1) s += __shfl_xor(s, m, 64);
    if (lane == 0) out[row] = s + b_out[0];
}

// ----------------------------------------------------------------
extern "C" void kernel_launch(void* const* d_in, const int* in_sizes, int n_in,
                              void* d_out, int out_size, void* d_ws, size_t ws_size,
                              hipStream_t stream)
{
    const float* xs    = (const float*)d_in[0];
    const float* ys    = (const float*)d_in[1];
    const float* W_in  = (const float*)d_in[2];
    const float* b_in  = (const float*)d_in[3];
    const float* Wq    = (const float*)d_in[4];
    const float* Wk    = (const float*)d_in[5];
    const float* Wv    = (const float*)d_in[6];
    const float* g1    = (const float*)d_in[7];
    const float* be1   = (const float*)d_in[8];
    const float* W1    = (const float*)d_in[9];
    const float* b1    = (const float*)d_in[10];
    const float* W2    = (const float*)d_in[11];
    const float* b2    = (const float*)d_in[12];
    const float* g2    = (const float*)d_in[13];
    const float* be2   = (const float*)d_in[14];
    const float* W_out = (const float*)d_in[15];
    const float* b_out = (const float*)d_in[16];
    (void)in_sizes; (void)n_in; (void)out_size; (void)ws_size;

    const size_t SZ = (size_t)NB * NTOK * E;
    float*  H   = (float*)d_ws;
    ushort* Hb  = (ushort*)(H + SZ);
    ushort* Qb  = Hb + SZ;
    ushort* Kb  = Qb + SZ;
    ushort* VTg = Kb + SZ;                          // [b][e][tok]
    ushort* WT  = VTg + SZ;                         // 60 x 64K bf16 transposed weights

    k_wprep<<<dim3(NLAYER * 5), dim3(256), 0, stream>>>(Wq, Wk, Wv, W1, W2, WT);
    k_embed<<<dim3(2048), dim3(256), 0, stream>>>(xs, ys, W_in, b_in, H, Hb);
    for (int i = 0; i < NLAYER; ++i) {
        const size_t vo = (size_t)i * E;
        const ushort* WqT = WT + ((size_t)(i * 5 + 0) << 16);
        const ushort* WkT = WT + ((size_t)(i * 5 + 1) << 16);
        const ushort* WvT = WT + ((size_t)(i * 5 + 2) << 16);
        const ushort* W1T = WT + ((size_t)(i * 5 + 3) << 16);
        const ushort* W2T = WT + ((size_t)(i * 5 + 4) << 16);
        k_qkv<<<dim3(512), dim3(256), 0, stream>>>(Hb, WqT, WkT, WvT, Qb, Kb, VTg);
        k_attn<<<dim3(512), dim3(256), 0, stream>>>(Qb, Kb, VTg, H, Hb, g1 + vo, be1 + vo);
        k_mlp<<<dim3(512), dim3(256), 0, stream>>>(Hb, H, Hb, W1T, b1 + vo, W2T, b2 + vo,
                                                   g2 + vo, be2 + vo);
    }
    k_readout<<<dim3((NB * NTOK) / 4), dim3(256), 0, stream>>>(H, W_out, b_out, (float*)d_out);
}

// Round 7
// 1955.114 us; speedup vs baseline: 2.2952x; 1.3898x over previous
//
#include <hip/hip_runtime.h>
#include <math.h>

#define E 256
#define NTOK 1024
#define NB 32
#define NLAYER 12
#define LN_EPS 1e-5f

typedef __attribute__((ext_vector_type(8))) short bf16x8;
typedef __attribute__((ext_vector_type(4))) float f32x4;
#define MFMA16(a, b, c) __builtin_amdgcn_mfma_f32_16x16x32_bf16(a, b, c, 0, 0, 0)

__device__ __forceinline__ ushort f2bf(float f) {
    union { float f; unsigned u; } v; v.f = f;
    return (ushort)((v.u + 0x7fffu + ((v.u >> 16) & 1u)) >> 16);
}

// ---------------------------------------------------------------- weight prep
__global__ __launch_bounds__(256) void k_wprep(
    const float* __restrict__ Wq, const float* __restrict__ Wk, const float* __restrict__ Wv,
    const float* __restrict__ W1, const float* __restrict__ W2,
    ushort* __restrict__ WT)
{
    const int mat = blockIdx.x % 5;
    const int l   = blockIdx.x / 5;
    const float* src = (mat == 0 ? Wq : mat == 1 ? Wk : mat == 2 ? Wv : mat == 3 ? W1 : W2)
                       + (size_t)l * E * E;
    ushort* dst = WT + ((size_t)(l * 5 + mat) << 16);
    const int n = threadIdx.x;
    #pragma unroll
    for (int c = 0; c < 4; ++c) {
        #pragma unroll
        for (int j = 0; j < 8; ++j) {
            const int k0 = c * 64 + j * 8;
            uint4 u;
            u.x = (uint)f2bf(src[(size_t)(k0 + 0) * E + n]) | ((uint)f2bf(src[(size_t)(k0 + 1) * E + n]) << 16);
            u.y = (uint)f2bf(src[(size_t)(k0 + 2) * E + n]) | ((uint)f2bf(src[(size_t)(k0 + 3) * E + n]) << 16);
            u.z = (uint)f2bf(src[(size_t)(k0 + 4) * E + n]) | ((uint)f2bf(src[(size_t)(k0 + 5) * E + n]) << 16);
            u.w = (uint)f2bf(src[(size_t)(k0 + 6) * E + n]) | ((uint)f2bf(src[(size_t)(k0 + 7) * E + n]) << 16);
            *(uint4*)&dst[(size_t)n * E + k0] = u;
        }
    }
}

// ---------------------------------------------------------------- embed
__global__ __launch_bounds__(256) void k_embed(
    const float* __restrict__ xs, const float* __restrict__ ys,
    const float* __restrict__ W_in, const float* __restrict__ b_in,
    float* __restrict__ H, ushort* __restrict__ Hb)
{
    __shared__ float zs[16][64];
    const int tid = threadIdx.x;
    const int r0 = blockIdx.x * 16;
    #pragma unroll
    for (int l = 0; l < 4; ++l) {
        int lin = tid + l * 256;
        int i = lin >> 6, d = lin & 63;
        int row = r0 + i;
        int t = row & (NTOK - 1);
        float v;
        if (d < 63) v = xs[(size_t)row * 63 + d];
        else        v = (t == NTOK - 1) ? 0.f : ys[row];
        zs[i][d] = v;
    }
    __syncthreads();
    float acc[16];
    #pragma unroll
    for (int i = 0; i < 16; ++i) acc[i] = 0.f;
    for (int d = 0; d < 64; ++d) {
        float w = W_in[d * E + tid];
        #pragma unroll
        for (int i = 0; i < 16; ++i) acc[i] = fmaf(zs[i][d], w, acc[i]);
    }
    float bb = b_in[tid];
    #pragma unroll
    for (int i = 0; i < 16; ++i) {
        float o = acc[i] + bb;
        H [(size_t)(r0 + i) * E + tid] = o;
        Hb[(size_t)(r0 + i) * E + tid] = f2bf(o);
    }
}

// ---------------------------------------------------------------- qkv helpers (ALL static indexing)
__device__ __forceinline__ void qkv_gemm(
    const ushort* __restrict__ Wt, const ushort* __restrict__ Hb,
    size_t r0, int tid, int w, int lr, int lg,
    ushort (&Ws)[256][72], f32x4 (&acc)[4][4])
{
    #pragma unroll
    for (int mt = 0; mt < 4; ++mt)
        #pragma unroll
        for (int nt = 0; nt < 4; ++nt) acc[mt][nt] = (f32x4){0.f, 0.f, 0.f, 0.f};
    #pragma unroll 1
    for (int kc = 0; kc < 4; ++kc) {
        __syncthreads();                          // prev use of Ws done
        #pragma unroll
        for (int rep = 0; rep < 8; ++rep) {       // stage [256][64] weight chunk
            int lin = rep * 256 + tid;
            int n = lin >> 3, slot = lin & 7;
            bf16x8 v = *(const bf16x8*)&Wt[(size_t)n * E + kc * 64 + slot * 8];
            *(bf16x8*)&Ws[n][slot * 8] = v;
        }
        __syncthreads();
        #pragma unroll
        for (int kl = 0; kl < 2; ++kl) {
            bf16x8 af[4], bw[4];
            #pragma unroll
            for (int mt = 0; mt < 4; ++mt)
                af[mt] = *(const bf16x8*)&Hb[(r0 + mt * 16 + lr) * E + kc * 64 + kl * 32 + lg * 8];
            #pragma unroll
            for (int nt = 0; nt < 4; ++nt)
                bw[nt] = *(const bf16x8*)&Ws[w * 64 + nt * 16 + lr][kl * 32 + lg * 8];
            #pragma unroll
            for (int mt = 0; mt < 4; ++mt)
                #pragma unroll
                for (int nt = 0; nt < 4; ++nt)
                    acc[mt][nt] = MFMA16(af[mt], bw[nt], acc[mt][nt]);
        }
    }
}

__device__ __forceinline__ void qkv_out_qk(
    ushort* __restrict__ Out, size_t r0, int w, int l, int lr, int lg,
    ushort (&ScW)[16][72], f32x4 (&acc)[4][4])
{
    #pragma unroll
    for (int mt = 0; mt < 4; ++mt) {              // STATIC mt: acc stays in registers
        #pragma unroll
        for (int nt = 0; nt < 4; ++nt)
            #pragma unroll
            for (int r = 0; r < 4; ++r)
                ScW[lg * 4 + r][nt * 16 + lr] = f2bf(acc[mt][nt][r]);
        #pragma unroll
        for (int j = 0; j < 2; ++j) {             // same-wave RAW via LDS
            bf16x8 v = *(const bf16x8*)&ScW[l >> 2][(l & 3) * 16 + j * 8];
            *(bf16x8*)&Out[(r0 + mt * 16 + (l >> 2)) * E + w * 64 + (l & 3) * 16 + j * 8] = v;
        }
    }
}

// ---------------------------------------------------------------- MFMA qkv (register-blocked)
__global__ __launch_bounds__(256, 2) void k_qkv(
    const ushort* __restrict__ Hb,
    const ushort* __restrict__ WqT, const ushort* __restrict__ WkT, const ushort* __restrict__ WvT,
    ushort* __restrict__ Qb, ushort* __restrict__ Kb, ushort* __restrict__ VTg)
{
    __shared__ __align__(16) ushort Ws[256][72];    // weights chunk; reused as V out-stage
    __shared__ __align__(16) ushort Sc[4][16][72];  // per-wave Q/K out-scratch
    const int tid = threadIdx.x;
    const int w = tid >> 6, l = tid & 63;
    const int lr = l & 15, lg = l >> 4;
    const size_t r0 = (size_t)blockIdx.x * 64;
    const int b    = (int)(r0 >> 10);
    const int tok0 = (int)(r0 & (NTOK - 1));

    f32x4 acc[4][4];

    qkv_gemm(WqT, Hb, r0, tid, w, lr, lg, Ws, acc);
    qkv_out_qk(Qb, r0, w, l, lr, lg, Sc[w], acc);

    qkv_gemm(WkT, Hb, r0, tid, w, lr, lg, Ws, acc);
    qkv_out_qk(Kb, r0, w, l, lr, lg, Sc[w], acc);

    qkv_gemm(WvT, Hb, r0, tid, w, lr, lg, Ws, acc);
    // V epilogue: stage [e][tok] tile in Ws, then coalesced 128B copy-out
    __syncthreads();                              // all waves done reading weights
    #pragma unroll
    for (int mt = 0; mt < 4; ++mt)
        #pragma unroll
        for (int nt = 0; nt < 4; ++nt) {
            ushort4 u;
            u.x = f2bf(acc[mt][nt][0]); u.y = f2bf(acc[mt][nt][1]);
            u.z = f2bf(acc[mt][nt][2]); u.w = f2bf(acc[mt][nt][3]);
            *(ushort4*)&Ws[w * 64 + nt * 16 + lr][mt * 16 + lg * 4] = u;
        }
    __syncthreads();
    #pragma unroll
    for (int rep = 0; rep < 8; ++rep) {
        int lin = rep * 256 + tid;
        int row = lin >> 3, ch = lin & 7;         // 8 lanes = 128B contiguous per e-row
        bf16x8 v = *(const bf16x8*)&Ws[row][ch * 8];
        *(bf16x8*)&VTg[((size_t)b * E + row) * NTOK + tok0 + ch * 8] = v;
    }
}

// ---------------------------------------------------------------- MFMA attention + residual + LN1
// Double-buffered K/VT staging, one barrier per K-tile.
__global__ __launch_bounds__(256, 2) void k_attn(
    const ushort* __restrict__ Qb, const ushort* __restrict__ Kb, const ushort* __restrict__ VTg,
    float* __restrict__ H, ushort* __restrict__ HbO,
    const float* __restrict__ g1, const float* __restrict__ be1)
{
    __shared__ __align__(16) ushort Ks[2][32][264];
    __shared__ __align__(16) ushort VT[2][256][40];
    __shared__ __align__(16) ushort Pl[4][16][40];
    const int tid = threadIdx.x;
    const int w  = tid >> 6, l = tid & 63;
    const int lr = l & 15, lg = l >> 4;

    const int wq  = blockIdx.x;
    const int p   = wq >> 3;
    const int batch = ((wq & 7) << 2) | (p & 3);    // 4 batches per XCD (KV L2-pinned)
    const int qt  = p >> 2;

    const size_t kvbase = (size_t)batch * NTOK * E;
    const size_t vtbase = (size_t)batch * E * NTOK;
    const int    qrow0  = qt * 64 + w * 16;
    const size_t qbase  = kvbase + (size_t)qrow0 * E;

    bf16x8 qf[8];
    #pragma unroll
    for (int kk = 0; kk < 8; ++kk)
        qf[kk] = *(const bf16x8*)&Qb[qbase + (size_t)lr * E + kk * 32 + lg * 8];

    f32x4 o[16];
    #pragma unroll
    for (int nt = 0; nt < 16; ++nt) o[nt] = (f32x4){0.f, 0.f, 0.f, 0.f};

    const int skrow = tid >> 3;
    const int se0   = (tid & 7) * 32;
    const float inv_n = 1.0f / (float)NTOK;

    // prologue: stage tile 0 into buffer 0
    #pragma unroll
    for (int c = 0; c < 4; ++c) {
        bf16x8 kv = *(const bf16x8*)&Kb[kvbase + (size_t)skrow * E + se0 + c * 8];
        *(bf16x8*)&Ks[0][skrow][se0 + c * 8] = kv;
    }
    #pragma unroll
    for (int c = 0; c < 4; ++c) {
        bf16x8 vv = *(const bf16x8*)&VTg[vtbase + (size_t)tid * NTOK + c * 8];
        *(bf16x8*)&VT[0][tid][c * 8] = vv;
    }
    __syncthreads();

    for (int jt = 0; jt < 32; ++jt) {
        const int cur = jt & 1;
        if (jt < 31) {                                // prefetch next tile into cur^1
            const int k0n = (jt + 1) * 32;
            #pragma unroll
            for (int c = 0; c < 4; ++c) {
                bf16x8 kv = *(const bf16x8*)&Kb[kvbase + (size_t)(k0n + skrow) * E + se0 + c * 8];
                *(bf16x8*)&Ks[cur ^ 1][skrow][se0 + c * 8] = kv;
            }
            #pragma unroll
            for (int c = 0; c < 4; ++c) {
                bf16x8 vv = *(const bf16x8*)&VTg[vtbase + (size_t)tid * NTOK + k0n + c * 8];
                *(bf16x8*)&VT[cur ^ 1][tid][c * 8] = vv;
            }
        }

        f32x4 s0 = (f32x4){0.f, 0.f, 0.f, 0.f};
        f32x4 s1 = (f32x4){0.f, 0.f, 0.f, 0.f};
        #pragma unroll
        for (int kk = 0; kk < 8; ++kk) {
            bf16x8 b0 = *(const bf16x8*)&Ks[cur][lr][kk * 32 + lg * 8];
            bf16x8 b1 = *(const bf16x8*)&Ks[cur][16 + lr][kk * 32 + lg * 8];
            s0 = MFMA16(qf[kk], b0, s0);
            s1 = MFMA16(qf[kk], b1, s1);
        }
        #pragma unroll
        for (int r = 0; r < 4; ++r) {
            Pl[w][lg * 4 + r][lr]      = f2bf(fmaxf(s0[r], 0.f) * inv_n);
            Pl[w][lg * 4 + r][16 + lr] = f2bf(fmaxf(s1[r], 0.f) * inv_n);
        }
        bf16x8 pa = *(const bf16x8*)&Pl[w][lr][lg * 8];   // same-wave RAW
        #pragma unroll
        for (int nt = 0; nt < 16; ++nt) {
            bf16x8 vb = *(const bf16x8*)&VT[cur][nt * 16 + lr][lg * 8];
            o[nt] = MFMA16(pa, vb, o[nt]);
        }
        __syncthreads();   // staging of cur^1 visible; reads of cur done
    }

    float gg[16], bb[16];
    #pragma unroll
    for (int nt = 0; nt < 16; ++nt) {
        gg[nt] = g1[nt * 16 + lr];
        bb[nt] = be1[nt * 16 + lr];
    }
    #pragma unroll
    for (int r = 0; r < 4; ++r) {
        const int q = lg * 4 + r;
        const size_t rowbase = kvbase + (size_t)(qrow0 + q) * E;
        float xv[16];
        float s = 0.f, s2 = 0.f;
        #pragma unroll
        for (int nt = 0; nt < 16; ++nt) {
            float val = H[rowbase + nt * 16 + lr] + o[nt][r];
            xv[nt] = val;
            s += val; s2 += val * val;
        }
        #pragma unroll
        for (int m = 1; m < 16; m <<= 1) {
            s  += __shfl_xor(s, m, 64);
            s2 += __shfl_xor(s2, m, 64);
        }
        float mu = s * (1.f / 256.f);
        float rs = rsqrtf(s2 * (1.f / 256.f) - mu * mu + LN_EPS);
        #pragma unroll
        for (int nt = 0; nt < 16; ++nt) {
            float ov = (xv[nt] - mu) * rs * gg[nt] + bb[nt];
            H  [rowbase + nt * 16 + lr] = ov;
            HbO[rowbase + nt * 16 + lr] = f2bf(ov);
        }
    }
}

// ---------------------------------------------------------------- MFMA MLP (register-blocked) + residual + LN2
__global__ __launch_bounds__(256, 2) void k_mlp(
    const ushort* __restrict__ Hb, float* __restrict__ H, ushort* __restrict__ HbO,
    const ushort* __restrict__ W1T, const float* __restrict__ b1,
    const ushort* __restrict__ W2T, const float* __restrict__ b2,
    const float* __restrict__ g2, const float* __restrict__ be2)
{
    __shared__ __align__(16) ushort Ws[256][72];
    __shared__ __align__(16) ushort Ts[64][264];
    __shared__ float part[4][64][2];
    __shared__ float stats[64][2];
    const int tid = threadIdx.x;
    const int w = tid >> 6, l = tid & 63;
    const int lr = l & 15, lg = l >> 4;
    const size_t r0 = (size_t)blockIdx.x * 64;

    // ---- GEMM1: T = relu(H @ W1 + b1)
    f32x4 acc[4][4];
    qkv_gemm(W1T, Hb, r0, tid, w, lr, lg, Ws, acc);
    {
        float bb1[4];
        #pragma unroll
        for (int nt = 0; nt < 4; ++nt) bb1[nt] = b1[w * 64 + nt * 16 + lr];
        #pragma unroll
        for (int mt = 0; mt < 4; ++mt)
            #pragma unroll
            for (int nt = 0; nt < 4; ++nt)
                #pragma unroll
                for (int r = 0; r < 4; ++r)
                    Ts[mt * 16 + lg * 4 + r][w * 64 + nt * 16 + lr]
                        = f2bf(fmaxf(acc[mt][nt][r] + bb1[nt], 0.f));
    }

    // ---- GEMM2: out = T @ W2
    f32x4 acc2[4][4];
    #pragma unroll
    for (int mt = 0; mt < 4; ++mt)
        #pragma unroll
        for (int nt = 0; nt < 4; ++nt) acc2[mt][nt] = (f32x4){0.f, 0.f, 0.f, 0.f};
    #pragma unroll 1
    for (int kc = 0; kc < 4; ++kc) {
        __syncthreads();
        #pragma unroll
        for (int rep = 0; rep < 8; ++rep) {
            int lin = rep * 256 + tid;
            int n = lin >> 3, slot = lin & 7;
            bf16x8 v = *(const bf16x8*)&W2T[(size_t)n * E + kc * 64 + slot * 8];
            *(bf16x8*)&Ws[n][slot * 8] = v;
        }
        __syncthreads();
        #pragma unroll
        for (int kl = 0; kl < 2; ++kl) {
            bf16x8 af[4], bw[4];
            #pragma unroll
            for (int mt = 0; mt < 4; ++mt)
                af[mt] = *(const bf16x8*)&Ts[mt * 16 + lr][kc * 64 + kl * 32 + lg * 8];
            #pragma unroll
            for (int nt = 0; nt < 4; ++nt)
                bw[nt] = *(const bf16x8*)&Ws[w * 64 + nt * 16 + lr][kl * 32 + lg * 8];
            #pragma unroll
            for (int mt = 0; mt < 4; ++mt)
                #pragma unroll
                for (int nt = 0; nt < 4; ++nt)
                    acc2[mt][nt] = MFMA16(af[mt], bw[nt], acc2[mt][nt]);
        }
    }

    // ---- residual + LN2 (cross-wave row reduction)
    {
        float b2v[4];
        #pragma unroll
        for (int nt = 0; nt < 4; ++nt) b2v[nt] = b2[w * 64 + nt * 16 + lr];
        #pragma unroll
        for (int mt = 0; mt < 4; ++mt)
            #pragma unroll
            for (int r = 0; r < 4; ++r)
                #pragma unroll
                for (int nt = 0; nt < 4; ++nt)
                    acc2[mt][nt][r] += H[(r0 + mt * 16 + lg * 4 + r) * E + w * 64 + nt * 16 + lr]
                                       + b2v[nt];
    }
    #pragma unroll
    for (int mt = 0; mt < 4; ++mt)
        #pragma unroll
        for (int r = 0; r < 4; ++r) {
            float s = 0.f, s2 = 0.f;
            #pragma unroll
            for (int nt = 0; nt < 4; ++nt) {
                float v = acc2[mt][nt][r];
                s += v; s2 += v * v;
            }
            #pragma unroll
            for (int m = 1; m < 16; m <<= 1) {
                s  += __shfl_xor(s, m, 64);
                s2 += __shfl_xor(s2, m, 64);
            }
            if (lr == 0) {
                part[w][mt * 16 + lg * 4 + r][0] = s;
                part[w][mt * 16 + lg * 4 + r][1] = s2;
            }
        }
    __syncthreads();
    if (tid < 64) {
        float s = part[0][tid][0] + part[1][tid][0] + part[2][tid][0] + part[3][tid][0];
        float s2 = part[0][tid][1] + part[1][tid][1] + part[2][tid][1] + part[3][tid][1];
        float mu = s * (1.f / 256.f);
        stats[tid][0] = mu;
        stats[tid][1] = rsqrtf(s2 * (1.f / 256.f) - mu * mu + LN_EPS);
    }
    __syncthreads();
    {
        float gg[4], be[4];
        #pragma unroll
        for (int nt = 0; nt < 4; ++nt) {
            gg[nt] = g2[w * 64 + nt * 16 + lr];
            be[nt] = be2[w * 64 + nt * 16 + lr];
        }
        #pragma unroll
        for (int mt = 0; mt < 4; ++mt)
            #pragma unroll
            for (int r = 0; r < 4; ++r) {
                const int row = mt * 16 + lg * 4 + r;
                const float mu = stats[row][0], rs = stats[row][1];
                const size_t rowbase = (r0 + row) * E;
                #pragma unroll
                for (int nt = 0; nt < 4; ++nt) {
                    float ov = (acc2[mt][nt][r] - mu) * rs * gg[nt] + be[nt];
                    H  [rowbase + w * 64 + nt * 16 + lr] = ov;
                    HbO[rowbase + w * 64 + nt * 16 + lr] = f2bf(ov);
                }
            }
    }
}

// ---------------------------------------------------------------- readout
__global__ __launch_bounds__(256) void k_readout(
    const float* __restrict__ H, const float* __restrict__ W_out,
    const float* __restrict__ b_out, float* __restrict__ out)
{
    const int tid = threadIdx.x;
    const int lane = tid & 63;
    const int row = blockIdx.x * 4 + (tid >> 6);
    float s = 0.f;
    #pragma unroll
    for (int j = 0; j < 4; ++j)
        s += H[(size_t)row * E + j * 64 + lane] * W_out[j * 64 + lane];
    #pragma unroll
    for (int m = 1; m < 64; m <<= 1) s += __shfl_xor(s, m, 64);
    if (lane == 0) out[row] = s + b_out[0];
}

// ----------------------------------------------------------------
extern "C" void kernel_launch(void* const* d_in, const int* in_sizes, int n_in,
                              void* d_out, int out_size, void* d_ws, size_t ws_size,
                              hipStream_t stream)
{
    const float* xs    = (const float*)d_in[0];
    const float* ys    = (const float*)d_in[1];
    const float* W_in  = (const float*)d_in[2];
    const float* b_in  = (const float*)d_in[3];
    const float* Wq    = (const float*)d_in[4];
    const float* Wk    = (const float*)d_in[5];
    const float* Wv    = (const float*)d_in[6];
    const float* g1    = (const float*)d_in[7];
    const float* be1   = (const float*)d_in[8];
    const float* W1    = (const float*)d_in[9];
    const float* b1    = (const float*)d_in[10];
    const float* W2    = (const float*)d_in[11];
    const float* b2    = (const float*)d_in[12];
    const float* g2    = (const float*)d_in[13];
    const float* be2   = (const float*)d_in[14];
    const float* W_out = (const float*)d_in[15];
    const float* b_out = (const float*)d_in[16];
    (void)in_sizes; (void)n_in; (void)out_size; (void)ws_size;

    const size_t SZ = (size_t)NB * NTOK * E;
    float*  H   = (float*)d_ws;
    ushort* Hb  = (ushort*)(H + SZ);
    ushort* Qb  = Hb + SZ;
    ushort* Kb  = Qb + SZ;
    ushort* VTg = Kb + SZ;                          // [b][e][tok]
    ushort* WT  = VTg + SZ;                         // 60 x 64K bf16 transposed weights

    k_wprep<<<dim3(NLAYER * 5), dim3(256), 0, stream>>>(Wq, Wk, Wv, W1, W2, WT);
    k_embed<<<dim3(2048), dim3(256), 0, stream>>>(xs, ys, W_in, b_in, H, Hb);
    for (int i = 0; i < NLAYER; ++i) {
        const size_t vo = (size_t)i * E;
        const ushort* WqT = WT + ((size_t)(i * 5 + 0) << 16);
        const ushort* WkT = WT + ((size_t)(i * 5 + 1) << 16);
        const ushort* WvT = WT + ((size_t)(i * 5 + 2) << 16);
        const ushort* W1T = WT + ((size_t)(i * 5 + 3) << 16);
        const ushort* W2T = WT + ((size_t)(i * 5 + 4) << 16);
        k_qkv<<<dim3(512), dim3(256), 0, stream>>>(Hb, WqT, WkT, WvT, Qb, Kb, VTg);
        k_attn<<<dim3(512), dim3(256), 0, stream>>>(Qb, Kb, VTg, H, Hb, g1 + vo, be1 + vo);
        k_mlp<<<dim3(512), dim3(256), 0, stream>>>(Hb, H, Hb, W1T, b1 + vo, W2T, b2 + vo,
                                                   g2 + vo, be2 + vo);
    }
    k_readout<<<dim3((NB * NTOK) / 4), dim3(256), 0, stream>>>(H, W_out, b_out, (float*)d_out);
}

// Round 9
// 1780.362 us; speedup vs baseline: 2.5205x; 1.0982x over previous
//
#include <hip/hip_runtime.h>
#include <math.h>

#define E 256
#define NTOK 1024
#define NB 32
#define NLAYER 12
#define LN_EPS 1e-5f

typedef __attribute__((ext_vector_type(8))) short bf16x8;
typedef __attribute__((ext_vector_type(4))) float f32x4;
#define MFMA16(a, b, c) __builtin_amdgcn_mfma_f32_16x16x32_bf16(a, b, c, 0, 0, 0)

__device__ __forceinline__ ushort f2bf(float f) {
    union { float f; unsigned u; } v; v.f = f;
    return (ushort)((v.u + 0x7fffu + ((v.u >> 16) & 1u)) >> 16);
}

// ---------------------------------------------------------------- weight prep
__global__ __launch_bounds__(256) void k_wprep(
    const float* __restrict__ Wq, const float* __restrict__ Wk, const float* __restrict__ Wv,
    const float* __restrict__ W1, const float* __restrict__ W2,
    ushort* __restrict__ WT)
{
    const int mat = blockIdx.x % 5;
    const int l   = blockIdx.x / 5;
    const float* src = (mat == 0 ? Wq : mat == 1 ? Wk : mat == 2 ? Wv : mat == 3 ? W1 : W2)
                       + (size_t)l * E * E;
    ushort* dst = WT + ((size_t)(l * 5 + mat) << 16);
    const int n = threadIdx.x;
    #pragma unroll
    for (int c = 0; c < 4; ++c) {
        #pragma unroll
        for (int j = 0; j < 8; ++j) {
            const int k0 = c * 64 + j * 8;
            uint4 u;
            u.x = (uint)f2bf(src[(size_t)(k0 + 0) * E + n]) | ((uint)f2bf(src[(size_t)(k0 + 1) * E + n]) << 16);
            u.y = (uint)f2bf(src[(size_t)(k0 + 2) * E + n]) | ((uint)f2bf(src[(size_t)(k0 + 3) * E + n]) << 16);
            u.z = (uint)f2bf(src[(size_t)(k0 + 4) * E + n]) | ((uint)f2bf(src[(size_t)(k0 + 5) * E + n]) << 16);
            u.w = (uint)f2bf(src[(size_t)(k0 + 6) * E + n]) | ((uint)f2bf(src[(size_t)(k0 + 7) * E + n]) << 16);
            *(uint4*)&dst[(size_t)n * E + k0] = u;
        }
    }
}

// ---------------------------------------------------------------- embed
__global__ __launch_bounds__(256) void k_embed(
    const float* __restrict__ xs, const float* __restrict__ ys,
    const float* __restrict__ W_in, const float* __restrict__ b_in,
    float* __restrict__ H, ushort* __restrict__ Hb)
{
    __shared__ float zs[16][64];
    const int tid = threadIdx.x;
    const int r0 = blockIdx.x * 16;
    #pragma unroll
    for (int l = 0; l < 4; ++l) {
        int lin = tid + l * 256;
        int i = lin >> 6, d = lin & 63;
        int row = r0 + i;
        int t = row & (NTOK - 1);
        float v;
        if (d < 63) v = xs[(size_t)row * 63 + d];
        else        v = (t == NTOK - 1) ? 0.f : ys[row];
        zs[i][d] = v;
    }
    __syncthreads();
    float acc[16];
    #pragma unroll
    for (int i = 0; i < 16; ++i) acc[i] = 0.f;
    for (int d = 0; d < 64; ++d) {
        float w = W_in[d * E + tid];
        #pragma unroll
        for (int i = 0; i < 16; ++i) acc[i] = fmaf(zs[i][d], w, acc[i]);
    }
    float bb = b_in[tid];
    #pragma unroll
    for (int i = 0; i < 16; ++i) {
        float o = acc[i] + bb;
        H [(size_t)(r0 + i) * E + tid] = o;
        Hb[(size_t)(r0 + i) * E + tid] = f2bf(o);
    }
}

// ---------------------------------------------------------------- qkv helpers (ALL static indexing)
__device__ __forceinline__ void qkv_gemm(
    const ushort* __restrict__ Wt, const ushort* __restrict__ Hb,
    size_t r0, int tid, int w, int lr, int lg,
    ushort (&Ws)[256][72], f32x4 (&acc)[4][4])
{
    #pragma unroll
    for (int mt = 0; mt < 4; ++mt)
        #pragma unroll
        for (int nt = 0; nt < 4; ++nt) acc[mt][nt] = (f32x4){0.f, 0.f, 0.f, 0.f};
    #pragma unroll 1
    for (int kc = 0; kc < 4; ++kc) {
        __syncthreads();                          // prev use of Ws done
        #pragma unroll
        for (int rep = 0; rep < 8; ++rep) {       // stage [256][64] weight chunk
            int lin = rep * 256 + tid;
            int n = lin >> 3, slot = lin & 7;
            bf16x8 v = *(const bf16x8*)&Wt[(size_t)n * E + kc * 64 + slot * 8];
            *(bf16x8*)&Ws[n][slot * 8] = v;
        }
        __syncthreads();
        #pragma unroll
        for (int kl = 0; kl < 2; ++kl) {
            bf16x8 af[4], bw[4];
            #pragma unroll
            for (int mt = 0; mt < 4; ++mt)
                af[mt] = *(const bf16x8*)&Hb[(r0 + mt * 16 + lr) * E + kc * 64 + kl * 32 + lg * 8];
            #pragma unroll
            for (int nt = 0; nt < 4; ++nt)
                bw[nt] = *(const bf16x8*)&Ws[w * 64 + nt * 16 + lr][kl * 32 + lg * 8];
            #pragma unroll
            for (int mt = 0; mt < 4; ++mt)
                #pragma unroll
                for (int nt = 0; nt < 4; ++nt)
                    acc[mt][nt] = MFMA16(af[mt], bw[nt], acc[mt][nt]);
        }
    }
}

__device__ __forceinline__ void qkv_out_qk(
    ushort* __restrict__ Out, size_t r0, int w, int l, int lr, int lg,
    ushort (&ScW)[16][72], f32x4 (&acc)[4][4])
{
    #pragma unroll
    for (int mt = 0; mt < 4; ++mt) {              // STATIC mt: acc stays in registers
        #pragma unroll
        for (int nt = 0; nt < 4; ++nt)
            #pragma unroll
            for (int r = 0; r < 4; ++r)
                ScW[lg * 4 + r][nt * 16 + lr] = f2bf(acc[mt][nt][r]);
        #pragma unroll
        for (int j = 0; j < 2; ++j) {             // same-wave RAW via LDS
            bf16x8 v = *(const bf16x8*)&ScW[l >> 2][(l & 3) * 16 + j * 8];
            *(bf16x8*)&Out[(r0 + mt * 16 + (l >> 2)) * E + w * 64 + (l & 3) * 16 + j * 8] = v;
        }
    }
}

// ---------------------------------------------------------------- MFMA qkv (register-blocked)
__global__ __launch_bounds__(256, 2) void k_qkv(
    const ushort* __restrict__ Hb,
    const ushort* __restrict__ WqT, const ushort* __restrict__ WkT, const ushort* __restrict__ WvT,
    ushort* __restrict__ Qb, ushort* __restrict__ Kb, ushort* __restrict__ VTg)
{
    __shared__ __align__(16) ushort Ws[256][72];    // weights chunk; reused as V out-stage
    __shared__ __align__(16) ushort Sc[4][16][72];  // per-wave Q/K out-scratch
    const int tid = threadIdx.x;
    const int w = tid >> 6, l = tid & 63;
    const int lr = l & 15, lg = l >> 4;
    const size_t r0 = (size_t)blockIdx.x * 64;
    const int b    = (int)(r0 >> 10);
    const int tok0 = (int)(r0 & (NTOK - 1));

    f32x4 acc[4][4];

    qkv_gemm(WqT, Hb, r0, tid, w, lr, lg, Ws, acc);
    qkv_out_qk(Qb, r0, w, l, lr, lg, Sc[w], acc);

    qkv_gemm(WkT, Hb, r0, tid, w, lr, lg, Ws, acc);
    qkv_out_qk(Kb, r0, w, l, lr, lg, Sc[w], acc);

    qkv_gemm(WvT, Hb, r0, tid, w, lr, lg, Ws, acc);
    // V epilogue: stage [e][tok] tile in Ws, then coalesced 128B copy-out
    __syncthreads();                              // all waves done reading weights
    #pragma unroll
    for (int mt = 0; mt < 4; ++mt)
        #pragma unroll
        for (int nt = 0; nt < 4; ++nt) {
            ushort4 u;
            u.x = f2bf(acc[mt][nt][0]); u.y = f2bf(acc[mt][nt][1]);
            u.z = f2bf(acc[mt][nt][2]); u.w = f2bf(acc[mt][nt][3]);
            *(ushort4*)&Ws[w * 64 + nt * 16 + lr][mt * 16 + lg * 4] = u;
        }
    __syncthreads();
    #pragma unroll
    for (int rep = 0; rep < 8; ++rep) {
        int lin = rep * 256 + tid;
        int row = lin >> 3, ch = lin & 7;         // 8 lanes = 128B contiguous per e-row
        bf16x8 v = *(const bf16x8*)&Ws[row][ch * 8];
        *(bf16x8*)&VTg[((size_t)b * E + row) * NTOK + tok0 + ch * 8] = v;
    }
}

// ---------------------------------------------------------------- MFMA attention + residual + LN1
// 128 q-rows/block, wave = 32 rows. SINGLE LDS buffer + two barriers per tile;
// next tile prefetched into REGISTERS during compute (T14 async-STAGE split):
// no concurrent LDS write/read overlap anywhere -> race-free by construction.
#define ATTN_LOAD_TILE(koff, ka, kb_, kc_, kd_, va_, vb_, vc_, vd_)                      \
    ka  = *(const bf16x8*)&Kb [kvbase + (size_t)((koff) +  0 + krow) * E + kch * 8];     \
    kb_ = *(const bf16x8*)&Kb [kvbase + (size_t)((koff) +  8 + krow) * E + kch * 8];     \
    kc_ = *(const bf16x8*)&Kb [kvbase + (size_t)((koff) + 16 + krow) * E + kch * 8];     \
    kd_ = *(const bf16x8*)&Kb [kvbase + (size_t)((koff) + 24 + krow) * E + kch * 8];     \
    va_ = *(const bf16x8*)&VTg[vtbase + (size_t)(  0 + vrow) * NTOK + (koff) + vch * 8]; \
    vb_ = *(const bf16x8*)&VTg[vtbase + (size_t)( 64 + vrow) * NTOK + (koff) + vch * 8]; \
    vc_ = *(const bf16x8*)&VTg[vtbase + (size_t)(128 + vrow) * NTOK + (koff) + vch * 8]; \
    vd_ = *(const bf16x8*)&VTg[vtbase + (size_t)(192 + vrow) * NTOK + (koff) + vch * 8];

__global__ __launch_bounds__(256, 1) void k_attn(
    const ushort* __restrict__ Qb, const ushort* __restrict__ Kb, const ushort* __restrict__ VTg,
    float* __restrict__ H, ushort* __restrict__ HbO,
    const float* __restrict__ g1, const float* __restrict__ be1)
{
    __shared__ __align__(16) ushort Ks[32][264];
    __shared__ __align__(16) ushort VT[256][40];
    __shared__ __align__(16) ushort Pl[4][32][40];
    const int tid = threadIdx.x;
    const int w  = tid >> 6, l = tid & 63;
    const int lr = l & 15, lg = l >> 4;

    // bid mod 8 = batch mod 8 -> all 8 q-tiles of a batch on one XCD (4MB KV = L2)
    const int bid   = blockIdx.x;
    const int batch = bid & 31;
    const int tile  = bid >> 5;

    const size_t kvbase = (size_t)batch * NTOK * E;
    const size_t vtbase = (size_t)batch * E * NTOK;
    const int    qrow0  = tile * 128 + w * 32;
    const size_t qbase  = kvbase + (size_t)qrow0 * E;

    // Q fragments: 2 row-tiles x 8 kk, register-resident
    bf16x8 qf[2][8];
    #pragma unroll
    for (int rt = 0; rt < 2; ++rt)
        #pragma unroll
        for (int kk = 0; kk < 8; ++kk)
            qf[rt][kk] = *(const bf16x8*)&Qb[qbase + (size_t)(rt * 16 + lr) * E + kk * 32 + lg * 8];

    f32x4 o[2][16];
    #pragma unroll
    for (int rt = 0; rt < 2; ++rt)
        #pragma unroll
        for (int nt = 0; nt < 16; ++nt) o[rt][nt] = (f32x4){0.f, 0.f, 0.f, 0.f};

    const float inv_n = 1.0f / (float)NTOK;
    // Pl column swizzle: XOR 8-chunk by bit3 of q-row
    const int wsw = (lg >> 1) << 3;               // write: q=rt*16+lg*4+r -> (q>>3)&1 = lg>>1
    const int rsw = ((lr >> 3) & 1) << 3;         // read:  q=rt*16+lr    -> (q>>3)&1 = (lr>>3)&1

    // staging lane map (row-contiguous global segments)
    const int krow = tid >> 5;                    // K: 8 rows x 32 chunks (512B/row)
    const int kch  = tid & 31;
    const int vrow = tid >> 2;                    // VT: 64 rows x 4 chunks (64B/row)
    const int vch  = tid & 3;

    // prologue: tile 0 -> registers
    bf16x8 cka, ckb, ckc, ckd, cva, cvb, cvc, cvd;
    ATTN_LOAD_TILE(0, cka, ckb, ckc, ckd, cva, cvb, cvc, cvd);

    #pragma unroll 1
    for (int jt = 0; jt < 32; ++jt) {
        __syncthreads();                          // prior compute's LDS reads done (WAR)
        // write current tile regs -> LDS (vmcnt wait auto-inserted)
        *(bf16x8*)&Ks[ 0 + krow][kch * 8] = cka;
        *(bf16x8*)&Ks[ 8 + krow][kch * 8] = ckb;
        *(bf16x8*)&Ks[16 + krow][kch * 8] = ckc;
        *(bf16x8*)&Ks[24 + krow][kch * 8] = ckd;
        *(bf16x8*)&VT[  0 + vrow][vch * 8] = cva;
        *(bf16x8*)&VT[ 64 + vrow][vch * 8] = cvb;
        *(bf16x8*)&VT[128 + vrow][vch * 8] = cvc;
        *(bf16x8*)&VT[192 + vrow][vch * 8] = cvd;
        // issue next tile's global loads (registers only; latency hides under MFMA)
        bf16x8 nka, nkb, nkc, nkd, nva, nvb, nvc, nvd;
        {
            const int kn = ((jt + 1) & 31) * 32;  // wraps at jt=31 (result unused)
            ATTN_LOAD_TILE(kn, nka, nkb, nkc, nkd, nva, nvb, nvc, nvd);
        }
        __syncthreads();                          // staging visible to all waves

        // S = Q K^T : 2 row-tiles x 2 col-tiles; Ks frags shared across row-tiles
        f32x4 s00 = (f32x4){0.f,0.f,0.f,0.f}, s01 = s00, s10 = s00, s11 = s00;
        #pragma unroll
        for (int kk = 0; kk < 8; ++kk) {
            bf16x8 b0 = *(const bf16x8*)&Ks[lr][kk * 32 + lg * 8];
            bf16x8 b1 = *(const bf16x8*)&Ks[16 + lr][kk * 32 + lg * 8];
            s00 = MFMA16(qf[0][kk], b0, s00);
            s01 = MFMA16(qf[0][kk], b1, s01);
            s10 = MFMA16(qf[1][kk], b0, s10);
            s11 = MFMA16(qf[1][kk], b1, s11);
        }
        // P = relu(S)/n -> Pl (col 8-chunk swizzled); same-wave write->read
        #pragma unroll
        for (int r = 0; r < 4; ++r) {
            Pl[w][lg * 4 + r]     [lr ^ wsw]        = f2bf(fmaxf(s00[r], 0.f) * inv_n);
            Pl[w][lg * 4 + r]     [(16 + lr) ^ wsw] = f2bf(fmaxf(s01[r], 0.f) * inv_n);
            Pl[w][16 + lg * 4 + r][lr ^ wsw]        = f2bf(fmaxf(s10[r], 0.f) * inv_n);
            Pl[w][16 + lg * 4 + r][(16 + lr) ^ wsw] = f2bf(fmaxf(s11[r], 0.f) * inv_n);
        }
        bf16x8 pa0 = *(const bf16x8*)&Pl[w][lr]     [(lg * 8) ^ rsw];
        bf16x8 pa1 = *(const bf16x8*)&Pl[w][16 + lr][(lg * 8) ^ rsw];
        // O += P V : VT frags shared across row-tiles
        #pragma unroll
        for (int nt = 0; nt < 16; ++nt) {
            bf16x8 vb = *(const bf16x8*)&VT[nt * 16 + lr][lg * 8];
            o[0][nt] = MFMA16(pa0, vb, o[0][nt]);
            o[1][nt] = MFMA16(pa1, vb, o[1][nt]);
        }
        // rotate prefetch regs
        cka = nka; ckb = nkb; ckc = nkc; ckd = nkd;
        cva = nva; cvb = nvb; cvc = nvc; cvd = nvd;
    }

    // epilogue: residual + LayerNorm (per row-tile)
    float gg[16], bb[16];
    #pragma unroll
    for (int nt = 0; nt < 16; ++nt) {
        gg[nt] = g1[nt * 16 + lr];
        bb[nt] = be1[nt * 16 + lr];
    }
    #pragma unroll
    for (int rt = 0; rt < 2; ++rt)
        #pragma unroll
        for (int r = 0; r < 4; ++r) {
            const int q = rt * 16 + lg * 4 + r;
            const size_t rowbase = kvbase + (size_t)(qrow0 + q) * E;
            float xv[16];
            float s = 0.f, s2 = 0.f;
            #pragma unroll
            for (int nt = 0; nt < 16; ++nt) {
                float val = H[rowbase + nt * 16 + lr] + o[rt][nt][r];
                xv[nt] = val;
                s += val; s2 += val * val;
            }
            #pragma unroll
            for (int m = 1; m < 16; m <<= 1) {
                s  += __shfl_xor(s, m, 64);
                s2 += __shfl_xor(s2, m, 64);
            }
            float mu = s * (1.f / 256.f);
            float rs = rsqrtf(s2 * (1.f / 256.f) - mu * mu + LN_EPS);
            #pragma unroll
            for (int nt = 0; nt < 16; ++nt) {
                float ov = (xv[nt] - mu) * rs * gg[nt] + bb[nt];
                H  [rowbase + nt * 16 + lr] = ov;
                HbO[rowbase + nt * 16 + lr] = f2bf(ov);
            }
        }
}

// ---------------------------------------------------------------- MFMA MLP (register-blocked) + residual + LN2
__global__ __launch_bounds__(256, 2) void k_mlp(
    const ushort* __restrict__ Hb, float* __restrict__ H, ushort* __restrict__ HbO,
    const ushort* __restrict__ W1T, const float* __restrict__ b1,
    const ushort* __restrict__ W2T, const float* __restrict__ b2,
    const float* __restrict__ g2, const float* __restrict__ be2)
{
    __shared__ __align__(16) ushort Ws[256][72];
    __shared__ __align__(16) ushort Ts[64][264];
    __shared__ float part[4][64][2];
    __shared__ float stats[64][2];
    const int tid = threadIdx.x;
    const int w = tid >> 6, l = tid & 63;
    const int lr = l & 15, lg = l >> 4;
    const size_t r0 = (size_t)blockIdx.x * 64;

    // ---- GEMM1: T = relu(H @ W1 + b1)
    f32x4 acc[4][4];
    qkv_gemm(W1T, Hb, r0, tid, w, lr, lg, Ws, acc);
    {
        float bb1[4];
        #pragma unroll
        for (int nt = 0; nt < 4; ++nt) bb1[nt] = b1[w * 64 + nt * 16 + lr];
        #pragma unroll
        for (int mt = 0; mt < 4; ++mt)
            #pragma unroll
            for (int nt = 0; nt < 4; ++nt)
                #pragma unroll
                for (int r = 0; r < 4; ++r)
                    Ts[mt * 16 + lg * 4 + r][w * 64 + nt * 16 + lr]
                        = f2bf(fmaxf(acc[mt][nt][r] + bb1[nt], 0.f));
    }

    // ---- GEMM2: out = T @ W2
    f32x4 acc2[4][4];
    #pragma unroll
    for (int mt = 0; mt < 4; ++mt)
        #pragma unroll
        for (int nt = 0; nt < 4; ++nt) acc2[mt][nt] = (f32x4){0.f, 0.f, 0.f, 0.f};
    #pragma unroll 1
    for (int kc = 0; kc < 4; ++kc) {
        __syncthreads();
        #pragma unroll
        for (int rep = 0; rep < 8; ++rep) {
            int lin = rep * 256 + tid;
            int n = lin >> 3, slot = lin & 7;
            bf16x8 v = *(const bf16x8*)&W2T[(size_t)n * E + kc * 64 + slot * 8];
            *(bf16x8*)&Ws[n][slot * 8] = v;
        }
        __syncthreads();
        #pragma unroll
        for (int kl = 0; kl < 2; ++kl) {
            bf16x8 af[4], bw[4];
            #pragma unroll
            for (int mt = 0; mt < 4; ++mt)
                af[mt] = *(const bf16x8*)&Ts[mt * 16 + lr][kc * 64 + kl * 32 + lg * 8];
            #pragma unroll
            for (int nt = 0; nt < 4; ++nt)
                bw[nt] = *(const bf16x8*)&Ws[w * 64 + nt * 16 + lr][kl * 32 + lg * 8];
            #pragma unroll
            for (int mt = 0; mt < 4; ++mt)
                #pragma unroll
                for (int nt = 0; nt < 4; ++nt)
                    acc2[mt][nt] = MFMA16(af[mt], bw[nt], acc2[mt][nt]);
        }
    }

    // ---- residual + LN2 (cross-wave row reduction)
    {
        float b2v[4];
        #pragma unroll
        for (int nt = 0; nt < 4; ++nt) b2v[nt] = b2[w * 64 + nt * 16 + lr];
        #pragma unroll
        for (int mt = 0; mt < 4; ++mt)
            #pragma unroll
            for (int r = 0; r < 4; ++r)
                #pragma unroll
                for (int nt = 0; nt < 4; ++nt)
                    acc2[mt][nt][r] += H[(r0 + mt * 16 + lg * 4 + r) * E + w * 64 + nt * 16 + lr]
                                       + b2v[nt];
    }
    #pragma unroll
    for (int mt = 0; mt < 4; ++mt)
        #pragma unroll
        for (int r = 0; r < 4; ++r) {
            float s = 0.f, s2 = 0.f;
            #pragma unroll
            for (int nt = 0; nt < 4; ++nt) {
                float v = acc2[mt][nt][r];
                s += v; s2 += v * v;
            }
            #pragma unroll
            for (int m = 1; m < 16; m <<= 1) {
                s  += __shfl_xor(s, m, 64);
                s2 += __shfl_xor(s2, m, 64);
            }
            if (lr == 0) {
                part[w][mt * 16 + lg * 4 + r][0] = s;
                part[w][mt * 16 + lg * 4 + r][1] = s2;
            }
        }
    __syncthreads();
    if (tid < 64) {
        float s = part[0][tid][0] + part[1][tid][0] + part[2][tid][0] + part[3][tid][0];
        float s2 = part[0][tid][1] + part[1][tid][1] + part[2][tid][1] + part[3][tid][1];
        float mu = s * (1.f / 256.f);
        stats[tid][0] = mu;
        stats[tid][1] = rsqrtf(s2 * (1.f / 256.f) - mu * mu + LN_EPS);
    }
    __syncthreads();
    {
        float gg[4], be[4];
        #pragma unroll
        for (int nt = 0; nt < 4; ++nt) {
            gg[nt] = g2[w * 64 + nt * 16 + lr];
            be[nt] = be2[w * 64 + nt * 16 + lr];
        }
        #pragma unroll
        for (int mt = 0; mt < 4; ++mt)
            #pragma unroll
            for (int r = 0; r < 4; ++r) {
                const int row = mt * 16 + lg * 4 + r;
                const float mu = stats[row][0], rs = stats[row][1];
                const size_t rowbase = (r0 + row) * E;
                #pragma unroll
                for (int nt = 0; nt < 4; ++nt) {
                    float ov = (acc2[mt][nt][r] - mu) * rs * gg[nt] + be[nt];
                    H  [rowbase + w * 64 + nt * 16 + lr] = ov;
                    HbO[rowbase + w * 64 + nt * 16 + lr] = f2bf(ov);
                }
            }
    }
}

// ---------------------------------------------------------------- readout
__global__ __launch_bounds__(256) void k_readout(
    const float* __restrict__ H, const float* __restrict__ W_out,
    const float* __restrict__ b_out, float* __restrict__ out)
{
    const int tid = threadIdx.x;
    const int lane = tid & 63;
    const int row = blockIdx.x * 4 + (tid >> 6);
    float s = 0.f;
    #pragma unroll
    for (int j = 0; j < 4; ++j)
        s += H[(size_t)row * E + j * 64 + lane] * W_out[j * 64 + lane];
    #pragma unroll
    for (int m = 1; m < 64; m <<= 1) s += __shfl_xor(s, m, 64);
    if (lane == 0) out[row] = s + b_out[0];
}

// ----------------------------------------------------------------
extern "C" void kernel_launch(void* const* d_in, const int* in_sizes, int n_in,
                              void* d_out, int out_size, void* d_ws, size_t ws_size,
                              hipStream_t stream)
{
    const float* xs    = (const float*)d_in[0];
    const float* ys    = (const float*)d_in[1];
    const float* W_in  = (const float*)d_in[2];
    const float* b_in  = (const float*)d_in[3];
    const float* Wq    = (const float*)d_in[4];
    const float* Wk    = (const float*)d_in[5];
    const float* Wv    = (const float*)d_in[6];
    const float* g1    = (const float*)d_in[7];
    const float* be1   = (const float*)d_in[8];
    const float* W1    = (const float*)d_in[9];
    const float* b1    = (const float*)d_in[10];
    const float* W2    = (const float*)d_in[11];
    const float* b2    = (const float*)d_in[12];
    const float* g2    = (const float*)d_in[13];
    const float* be2   = (const float*)d_in[14];
    const float* W_out = (const float*)d_in[15];
    const float* b_out = (const float*)d_in[16];
    (void)in_sizes; (void)n_in; (void)out_size; (void)ws_size;

    const size_t SZ = (size_t)NB * NTOK * E;
    float*  H   = (float*)d_ws;
    ushort* Hb  = (ushort*)(H + SZ);
    ushort* Qb  = Hb + SZ;
    ushort* Kb  = Qb + SZ;
    ushort* VTg = Kb + SZ;                          // [b][e][tok]
    ushort* WT  = VTg + SZ;                         // 60 x 64K bf16 transposed weights

    k_wprep<<<dim3(NLAYER * 5), dim3(256), 0, stream>>>(Wq, Wk, Wv, W1, W2, WT);
    k_embed<<<dim3(2048), dim3(256), 0, stream>>>(xs, ys, W_in, b_in, H, Hb);
    for (int i = 0; i < NLAYER; ++i) {
        const size_t vo = (size_t)i * E;
        const ushort* WqT = WT + ((size_t)(i * 5 + 0) << 16);
        const ushort* WkT = WT + ((size_t)(i * 5 + 1) << 16);
        const ushort* WvT = WT + ((size_t)(i * 5 + 2) << 16);
        const ushort* W1T = WT + ((size_t)(i * 5 + 3) << 16);
        const ushort* W2T = WT + ((size_t)(i * 5 + 4) << 16);
        k_qkv<<<dim3(512), dim3(256), 0, stream>>>(Hb, WqT, WkT, WvT, Qb, Kb, VTg);
        k_attn<<<dim3(256), dim3(256), 0, stream>>>(Qb, Kb, VTg, H, Hb, g1 + vo, be1 + vo);
        k_mlp<<<dim3(512), dim3(256), 0, stream>>>(Hb, H, Hb, W1T, b1 + vo, W2T, b2 + vo,
                                                   g2 + vo, be2 + vo);
    }
    k_readout<<<dim3((NB * NTOK) / 4), dim3(256), 0, stream>>>(H, W_out, b_out, (float*)d_out);
}

// Round 10
// 1731.385 us; speedup vs baseline: 2.5918x; 1.0283x over previous
//
#include <hip/hip_runtime.h>
#include <math.h>

#define E 256
#define NTOK 1024
#define NB 32
#define NLAYER 12
#define LN_EPS 1e-5f

typedef __attribute__((ext_vector_type(8))) short bf16x8;
typedef __attribute__((ext_vector_type(4))) float f32x4;
#define MFMA16(a, b, c) __builtin_amdgcn_mfma_f32_16x16x32_bf16(a, b, c, 0, 0, 0)

__device__ __forceinline__ ushort f2bf(float f) {
    union { float f; unsigned u; } v; v.f = f;
    return (ushort)((v.u + 0x7fffu + ((v.u >> 16) & 1u)) >> 16);
}

// ---------------------------------------------------------------- weight prep
__global__ __launch_bounds__(256) void k_wprep(
    const float* __restrict__ Wq, const float* __restrict__ Wk, const float* __restrict__ Wv,
    const float* __restrict__ W1, const float* __restrict__ W2,
    ushort* __restrict__ WT)
{
    const int mat = blockIdx.x % 5;
    const int l   = blockIdx.x / 5;
    const float* src = (mat == 0 ? Wq : mat == 1 ? Wk : mat == 2 ? Wv : mat == 3 ? W1 : W2)
                       + (size_t)l * E * E;
    ushort* dst = WT + ((size_t)(l * 5 + mat) << 16);
    const int n = threadIdx.x;
    #pragma unroll
    for (int c = 0; c < 4; ++c) {
        #pragma unroll
        for (int j = 0; j < 8; ++j) {
            const int k0 = c * 64 + j * 8;
            uint4 u;
            u.x = (uint)f2bf(src[(size_t)(k0 + 0) * E + n]) | ((uint)f2bf(src[(size_t)(k0 + 1) * E + n]) << 16);
            u.y = (uint)f2bf(src[(size_t)(k0 + 2) * E + n]) | ((uint)f2bf(src[(size_t)(k0 + 3) * E + n]) << 16);
            u.z = (uint)f2bf(src[(size_t)(k0 + 4) * E + n]) | ((uint)f2bf(src[(size_t)(k0 + 5) * E + n]) << 16);
            u.w = (uint)f2bf(src[(size_t)(k0 + 6) * E + n]) | ((uint)f2bf(src[(size_t)(k0 + 7) * E + n]) << 16);
            *(uint4*)&dst[(size_t)n * E + k0] = u;
        }
    }
}

// ---------------------------------------------------------------- embed
__global__ __launch_bounds__(256) void k_embed(
    const float* __restrict__ xs, const float* __restrict__ ys,
    const float* __restrict__ W_in, const float* __restrict__ b_in,
    float* __restrict__ H, ushort* __restrict__ Hb)
{
    __shared__ float zs[16][64];
    const int tid = threadIdx.x;
    const int r0 = blockIdx.x * 16;
    #pragma unroll
    for (int l = 0; l < 4; ++l) {
        int lin = tid + l * 256;
        int i = lin >> 6, d = lin & 63;
        int row = r0 + i;
        int t = row & (NTOK - 1);
        float v;
        if (d < 63) v = xs[(size_t)row * 63 + d];
        else        v = (t == NTOK - 1) ? 0.f : ys[row];
        zs[i][d] = v;
    }
    __syncthreads();
    float acc[16];
    #pragma unroll
    for (int i = 0; i < 16; ++i) acc[i] = 0.f;
    for (int d = 0; d < 64; ++d) {
        float w = W_in[d * E + tid];
        #pragma unroll
        for (int i = 0; i < 16; ++i) acc[i] = fmaf(zs[i][d], w, acc[i]);
    }
    float bb = b_in[tid];
    #pragma unroll
    for (int i = 0; i < 16; ++i) {
        float o = acc[i] + bb;
        H [(size_t)(r0 + i) * E + tid] = o;
        Hb[(size_t)(r0 + i) * E + tid] = f2bf(o);
    }
}

// ---------------------------------------------------------------- qkv helpers (ALL static indexing)
__device__ __forceinline__ void qkv_gemm(
    const ushort* __restrict__ Wt, const ushort* __restrict__ Hb,
    size_t r0, int tid, int w, int lr, int lg,
    ushort (&Ws)[256][72], f32x4 (&acc)[4][4])
{
    #pragma unroll
    for (int mt = 0; mt < 4; ++mt)
        #pragma unroll
        for (int nt = 0; nt < 4; ++nt) acc[mt][nt] = (f32x4){0.f, 0.f, 0.f, 0.f};
    #pragma unroll 1
    for (int kc = 0; kc < 4; ++kc) {
        __syncthreads();                          // prev use of Ws done
        #pragma unroll
        for (int rep = 0; rep < 8; ++rep) {       // stage [256][64] weight chunk
            int lin = rep * 256 + tid;
            int n = lin >> 3, slot = lin & 7;
            bf16x8 v = *(const bf16x8*)&Wt[(size_t)n * E + kc * 64 + slot * 8];
            *(bf16x8*)&Ws[n][slot * 8] = v;
        }
        __syncthreads();
        #pragma unroll
        for (int kl = 0; kl < 2; ++kl) {
            bf16x8 af[4], bw[4];
            #pragma unroll
            for (int mt = 0; mt < 4; ++mt)
                af[mt] = *(const bf16x8*)&Hb[(r0 + mt * 16 + lr) * E + kc * 64 + kl * 32 + lg * 8];
            #pragma unroll
            for (int nt = 0; nt < 4; ++nt)
                bw[nt] = *(const bf16x8*)&Ws[w * 64 + nt * 16 + lr][kl * 32 + lg * 8];
            #pragma unroll
            for (int mt = 0; mt < 4; ++mt)
                #pragma unroll
                for (int nt = 0; nt < 4; ++nt)
                    acc[mt][nt] = MFMA16(af[mt], bw[nt], acc[mt][nt]);
        }
    }
}

__device__ __forceinline__ void qkv_out_qk(
    ushort* __restrict__ Out, size_t r0, int w, int l, int lr, int lg,
    ushort (&ScW)[16][72], f32x4 (&acc)[4][4])
{
    #pragma unroll
    for (int mt = 0; mt < 4; ++mt) {              // STATIC mt: acc stays in registers
        #pragma unroll
        for (int nt = 0; nt < 4; ++nt)
            #pragma unroll
            for (int r = 0; r < 4; ++r)
                ScW[lg * 4 + r][nt * 16 + lr] = f2bf(acc[mt][nt][r]);
        #pragma unroll
        for (int j = 0; j < 2; ++j) {             // same-wave RAW via LDS
            bf16x8 v = *(const bf16x8*)&ScW[l >> 2][(l & 3) * 16 + j * 8];
            *(bf16x8*)&Out[(r0 + mt * 16 + (l >> 2)) * E + w * 64 + (l & 3) * 16 + j * 8] = v;
        }
    }
}

// ---------------------------------------------------------------- MFMA qkv (register-blocked)
__global__ __launch_bounds__(256, 2) void k_qkv(
    const ushort* __restrict__ Hb,
    const ushort* __restrict__ WqT, const ushort* __restrict__ WkT, const ushort* __restrict__ WvT,
    ushort* __restrict__ Qb, ushort* __restrict__ Kb, ushort* __restrict__ VTg)
{
    __shared__ __align__(16) ushort Ws[256][72];    // weights chunk; reused as V out-stage
    __shared__ __align__(16) ushort Sc[4][16][72];  // per-wave Q/K out-scratch
    const int tid = threadIdx.x;
    const int w = tid >> 6, l = tid & 63;
    const int lr = l & 15, lg = l >> 4;
    const size_t r0 = (size_t)blockIdx.x * 64;
    const int b    = (int)(r0 >> 10);
    const int tok0 = (int)(r0 & (NTOK - 1));

    f32x4 acc[4][4];

    qkv_gemm(WqT, Hb, r0, tid, w, lr, lg, Ws, acc);
    qkv_out_qk(Qb, r0, w, l, lr, lg, Sc[w], acc);

    qkv_gemm(WkT, Hb, r0, tid, w, lr, lg, Ws, acc);
    qkv_out_qk(Kb, r0, w, l, lr, lg, Sc[w], acc);

    qkv_gemm(WvT, Hb, r0, tid, w, lr, lg, Ws, acc);
    // V epilogue: stage [e][tok] tile in Ws, then coalesced 128B copy-out
    __syncthreads();                              // all waves done reading weights
    #pragma unroll
    for (int mt = 0; mt < 4; ++mt)
        #pragma unroll
        for (int nt = 0; nt < 4; ++nt) {
            ushort4 u;
            u.x = f2bf(acc[mt][nt][0]); u.y = f2bf(acc[mt][nt][1]);
            u.z = f2bf(acc[mt][nt][2]); u.w = f2bf(acc[mt][nt][3]);
            *(ushort4*)&Ws[w * 64 + nt * 16 + lr][mt * 16 + lg * 4] = u;
        }
    __syncthreads();
    #pragma unroll
    for (int rep = 0; rep < 8; ++rep) {
        int lin = rep * 256 + tid;
        int row = lin >> 3, ch = lin & 7;         // 8 lanes = 128B contiguous per e-row
        bf16x8 v = *(const bf16x8*)&Ws[row][ch * 8];
        *(bf16x8*)&VTg[((size_t)b * E + row) * NTOK + tok0 + ch * 8] = v;
    }
}

// ---------------------------------------------------------------- MFMA attention + residual + LN1
// 512 threads = 8 waves x 16 q-rows (block = 128 rows). 2 waves/SIMD for
// latency hiding (R9 was 1 wave/SIMD -> latency-bound at Occupancy=10%).
// Single LDS buffer + 2 barriers/tile; next tile prefetched into registers
// during compute (race-free by construction, R8 lesson).
#define ATTN_LOAD_TILE(koff, ka, kb_, va_, vb_)                                          \
    ka  = *(const bf16x8*)&Kb [kvbase + (size_t)((koff) + (tid >> 5)) * E + (tid & 31) * 8];       \
    kb_ = *(const bf16x8*)&Kb [kvbase + (size_t)((koff) + 16 + (tid >> 5)) * E + (tid & 31) * 8];  \
    va_ = *(const bf16x8*)&VTg[vtbase + (size_t)(tid >> 2) * NTOK + (koff) + (tid & 3) * 8];       \
    vb_ = *(const bf16x8*)&VTg[vtbase + (size_t)(128 + (tid >> 2)) * NTOK + (koff) + (tid & 3) * 8];

__global__ __launch_bounds__(512, 2) void k_attn(
    const ushort* __restrict__ Qb, const ushort* __restrict__ Kb, const ushort* __restrict__ VTg,
    float* __restrict__ H, ushort* __restrict__ HbO,
    const float* __restrict__ g1, const float* __restrict__ be1)
{
    __shared__ __align__(16) ushort Ks[32][264];
    __shared__ __align__(16) ushort VT[256][40];
    __shared__ __align__(16) ushort Pl[8][16][40];
    const int tid = threadIdx.x;
    const int w  = tid >> 6, l = tid & 63;
    const int lr = l & 15, lg = l >> 4;

    // bid mod 8 = batch mod 8 -> all 8 q-tiles of a batch on one XCD (4MB KV = L2)
    const int bid   = blockIdx.x;
    const int batch = bid & 31;
    const int tile  = bid >> 5;

    const size_t kvbase = (size_t)batch * NTOK * E;
    const size_t vtbase = (size_t)batch * E * NTOK;
    const int    qrow0  = tile * 128 + w * 16;
    const size_t qbase  = kvbase + (size_t)qrow0 * E;

    // Q fragments: 16 rows x 256, register-resident
    bf16x8 qf[8];
    #pragma unroll
    for (int kk = 0; kk < 8; ++kk)
        qf[kk] = *(const bf16x8*)&Qb[qbase + (size_t)lr * E + kk * 32 + lg * 8];

    f32x4 o[16];
    #pragma unroll
    for (int nt = 0; nt < 16; ++nt) o[nt] = (f32x4){0.f, 0.f, 0.f, 0.f};

    const float inv_n = 1.0f / (float)NTOK;
    // Pl column swizzle: XOR 8-chunk by bit3 of q-row
    const int wsw = ((lg >> 1) & 1) << 3;         // write: q = lg*4+r -> (q>>3)&1 = (lg>>1)&1
    const int rsw = ((lr >> 3) & 1) << 3;         // read:  q = lr    -> (q>>3)&1 = (lr>>3)&1

    // prologue: tile 0 -> registers (512 thr: 2 regs cover K, 2 cover VT)
    bf16x8 cka, ckb, cva, cvb;
    ATTN_LOAD_TILE(0, cka, ckb, cva, cvb);

    #pragma unroll 1
    for (int jt = 0; jt < 32; ++jt) {
        __syncthreads();                          // prior compute's LDS reads done (WAR)
        // write current tile regs -> LDS
        *(bf16x8*)&Ks[ 0 + (tid >> 5)][(tid & 31) * 8] = cka;
        *(bf16x8*)&Ks[16 + (tid >> 5)][(tid & 31) * 8] = ckb;
        *(bf16x8*)&VT[  0 + (tid >> 2)][(tid & 3) * 8] = cva;
        *(bf16x8*)&VT[128 + (tid >> 2)][(tid & 3) * 8] = cvb;
        // issue next tile's global loads (registers only; latency hides under MFMA)
        bf16x8 nka, nkb, nva, nvb;
        {
            const int kn = ((jt + 1) & 31) * 32;  // wraps at jt=31 (result unused)
            ATTN_LOAD_TILE(kn, nka, nkb, nva, nvb);
        }
        __syncthreads();                          // staging visible to all waves

        // S = Q K^T (two 16-col tiles)
        f32x4 s0 = (f32x4){0.f, 0.f, 0.f, 0.f};
        f32x4 s1 = (f32x4){0.f, 0.f, 0.f, 0.f};
        #pragma unroll
        for (int kk = 0; kk < 8; ++kk) {
            bf16x8 b0 = *(const bf16x8*)&Ks[lr][kk * 32 + lg * 8];
            bf16x8 b1 = *(const bf16x8*)&Ks[16 + lr][kk * 32 + lg * 8];
            s0 = MFMA16(qf[kk], b0, s0);
            s1 = MFMA16(qf[kk], b1, s1);
        }
        // P = relu(S)/n -> Pl (col 8-chunk swizzled); same-wave write->read
        #pragma unroll
        for (int r = 0; r < 4; ++r) {
            Pl[w][lg * 4 + r][lr ^ wsw]        = f2bf(fmaxf(s0[r], 0.f) * inv_n);
            Pl[w][lg * 4 + r][(16 + lr) ^ wsw] = f2bf(fmaxf(s1[r], 0.f) * inv_n);
        }
        bf16x8 pa = *(const bf16x8*)&Pl[w][lr][(lg * 8) ^ rsw];
        // O += P V
        #pragma unroll
        for (int nt = 0; nt < 16; ++nt) {
            bf16x8 vb = *(const bf16x8*)&VT[nt * 16 + lr][lg * 8];
            o[nt] = MFMA16(pa, vb, o[nt]);
        }
        // rotate prefetch regs
        cka = nka; ckb = nkb; cva = nva; cvb = nvb;
    }

    // epilogue: residual + LayerNorm
    float gg[16], bb[16];
    #pragma unroll
    for (int nt = 0; nt < 16; ++nt) {
        gg[nt] = g1[nt * 16 + lr];
        bb[nt] = be1[nt * 16 + lr];
    }
    #pragma unroll
    for (int r = 0; r < 4; ++r) {
        const int q = lg * 4 + r;
        const size_t rowbase = kvbase + (size_t)(qrow0 + q) * E;
        float xv[16];
        float s = 0.f, s2 = 0.f;
        #pragma unroll
        for (int nt = 0; nt < 16; ++nt) {
            float val = H[rowbase + nt * 16 + lr] + o[nt][r];
            xv[nt] = val;
            s += val; s2 += val * val;
        }
        #pragma unroll
        for (int m = 1; m < 16; m <<= 1) {
            s  += __shfl_xor(s, m, 64);
            s2 += __shfl_xor(s2, m, 64);
        }
        float mu = s * (1.f / 256.f);
        float rs = rsqrtf(s2 * (1.f / 256.f) - mu * mu + LN_EPS);
        #pragma unroll
        for (int nt = 0; nt < 16; ++nt) {
            float ov = (xv[nt] - mu) * rs * gg[nt] + bb[nt];
            H  [rowbase + nt * 16 + lr] = ov;
            HbO[rowbase + nt * 16 + lr] = f2bf(ov);
        }
    }
}

// ---------------------------------------------------------------- MFMA MLP (register-blocked) + residual + LN2
__global__ __launch_bounds__(256, 2) void k_mlp(
    const ushort* __restrict__ Hb, float* __restrict__ H, ushort* __restrict__ HbO,
    const ushort* __restrict__ W1T, const float* __restrict__ b1,
    const ushort* __restrict__ W2T, const float* __restrict__ b2,
    const float* __restrict__ g2, const float* __restrict__ be2)
{
    __shared__ __align__(16) ushort Ws[256][72];
    __shared__ __align__(16) ushort Ts[64][264];
    __shared__ float part[4][64][2];
    __shared__ float stats[64][2];
    const int tid = threadIdx.x;
    const int w = tid >> 6, l = tid & 63;
    const int lr = l & 15, lg = l >> 4;
    const size_t r0 = (size_t)blockIdx.x * 64;

    // ---- GEMM1: T = relu(H @ W1 + b1)
    f32x4 acc[4][4];
    qkv_gemm(W1T, Hb, r0, tid, w, lr, lg, Ws, acc);
    {
        float bb1[4];
        #pragma unroll
        for (int nt = 0; nt < 4; ++nt) bb1[nt] = b1[w * 64 + nt * 16 + lr];
        #pragma unroll
        for (int mt = 0; mt < 4; ++mt)
            #pragma unroll
            for (int nt = 0; nt < 4; ++nt)
                #pragma unroll
                for (int r = 0; r < 4; ++r)
                    Ts[mt * 16 + lg * 4 + r][w * 64 + nt * 16 + lr]
                        = f2bf(fmaxf(acc[mt][nt][r] + bb1[nt], 0.f));
    }

    // ---- GEMM2: out = T @ W2
    f32x4 acc2[4][4];
    #pragma unroll
    for (int mt = 0; mt < 4; ++mt)
        #pragma unroll
        for (int nt = 0; nt < 4; ++nt) acc2[mt][nt] = (f32x4){0.f, 0.f, 0.f, 0.f};
    #pragma unroll 1
    for (int kc = 0; kc < 4; ++kc) {
        __syncthreads();
        #pragma unroll
        for (int rep = 0; rep < 8; ++rep) {
            int lin = rep * 256 + tid;
            int n = lin >> 3, slot = lin & 7;
            bf16x8 v = *(const bf16x8*)&W2T[(size_t)n * E + kc * 64 + slot * 8];
            *(bf16x8*)&Ws[n][slot * 8] = v;
        }
        __syncthreads();
        #pragma unroll
        for (int kl = 0; kl < 2; ++kl) {
            bf16x8 af[4], bw[4];
            #pragma unroll
            for (int mt = 0; mt < 4; ++mt)
                af[mt] = *(const bf16x8*)&Ts[mt * 16 + lr][kc * 64 + kl * 32 + lg * 8];
            #pragma unroll
            for (int nt = 0; nt < 4; ++nt)
                bw[nt] = *(const bf16x8*)&Ws[w * 64 + nt * 16 + lr][kl * 32 + lg * 8];
            #pragma unroll
            for (int mt = 0; mt < 4; ++mt)
                #pragma unroll
                for (int nt = 0; nt < 4; ++nt)
                    acc2[mt][nt] = MFMA16(af[mt], bw[nt], acc2[mt][nt]);
        }
    }

    // ---- residual + LN2 (cross-wave row reduction)
    {
        float b2v[4];
        #pragma unroll
        for (int nt = 0; nt < 4; ++nt) b2v[nt] = b2[w * 64 + nt * 16 + lr];
        #pragma unroll
        for (int mt = 0; mt < 4; ++mt)
            #pragma unroll
            for (int r = 0; r < 4; ++r)
                #pragma unroll
                for (int nt = 0; nt < 4; ++nt)
                    acc2[mt][nt][r] += H[(r0 + mt * 16 + lg * 4 + r) * E + w * 64 + nt * 16 + lr]
                                       + b2v[nt];
    }
    #pragma unroll
    for (int mt = 0; mt < 4; ++mt)
        #pragma unroll
        for (int r = 0; r < 4; ++r) {
            float s = 0.f, s2 = 0.f;
            #pragma unroll
            for (int nt = 0; nt < 4; ++nt) {
                float v = acc2[mt][nt][r];
                s += v; s2 += v * v;
            }
            #pragma unroll
            for (int m = 1; m < 16; m <<= 1) {
                s  += __shfl_xor(s, m, 64);
                s2 += __shfl_xor(s2, m, 64);
            }
            if (lr == 0) {
                part[w][mt * 16 + lg * 4 + r][0] = s;
                part[w][mt * 16 + lg * 4 + r][1] = s2;
            }
        }
    __syncthreads();
    if (tid < 64) {
        float s = part[0][tid][0] + part[1][tid][0] + part[2][tid][0] + part[3][tid][0];
        float s2 = part[0][tid][1] + part[1][tid][1] + part[2][tid][1] + part[3][tid][1];
        float mu = s * (1.f / 256.f);
        stats[tid][0] = mu;
        stats[tid][1] = rsqrtf(s2 * (1.f / 256.f) - mu * mu + LN_EPS);
    }
    __syncthreads();
    {
        float gg[4], be[4];
        #pragma unroll
        for (int nt = 0; nt < 4; ++nt) {
            gg[nt] = g2[w * 64 + nt * 16 + lr];
            be[nt] = be2[w * 64 + nt * 16 + lr];
        }
        #pragma unroll
        for (int mt = 0; mt < 4; ++mt)
            #pragma unroll
            for (int r = 0; r < 4; ++r) {
                const int row = mt * 16 + lg * 4 + r;
                const float mu = stats[row][0], rs = stats[row][1];
                const size_t rowbase = (r0 + row) * E;
                #pragma unroll
                for (int nt = 0; nt < 4; ++nt) {
                    float ov = (acc2[mt][nt][r] - mu) * rs * gg[nt] + be[nt];
                    H  [rowbase + w * 64 + nt * 16 + lr] = ov;
                    HbO[rowbase + w * 64 + nt * 16 + lr] = f2bf(ov);
                }
            }
    }
}

// ---------------------------------------------------------------- readout
__global__ __launch_bounds__(256) void k_readout(
    const float* __restrict__ H, const float* __restrict__ W_out,
    const float* __restrict__ b_out, float* __restrict__ out)
{
    const int tid = threadIdx.x;
    const int lane = tid & 63;
    const int row = blockIdx.x * 4 + (tid >> 6);
    float s = 0.f;
    #pragma unroll
    for (int j = 0; j < 4; ++j)
        s += H[(size_t)row * E + j * 64 + lane] * W_out[j * 64 + lane];
    #pragma unroll
    for (int m = 1; m < 64; m <<= 1) s += __shfl_xor(s, m, 64);
    if (lane == 0) out[row] = s + b_out[0];
}

// ----------------------------------------------------------------
extern "C" void kernel_launch(void* const* d_in, const int* in_sizes, int n_in,
                              void* d_out, int out_size, void* d_ws, size_t ws_size,
                              hipStream_t stream)
{
    const float* xs    = (const float*)d_in[0];
    const float* ys    = (const float*)d_in[1];
    const float* W_in  = (const float*)d_in[2];
    const float* b_in  = (const float*)d_in[3];
    const float* Wq    = (const float*)d_in[4];
    const float* Wk    = (const float*)d_in[5];
    const float* Wv    = (const float*)d_in[6];
    const float* g1    = (const float*)d_in[7];
    const float* be1   = (const float*)d_in[8];
    const float* W1    = (const float*)d_in[9];
    const float* b1    = (const float*)d_in[10];
    const float* W2    = (const float*)d_in[11];
    const float* b2    = (const float*)d_in[12];
    const float* g2    = (const float*)d_in[13];
    const float* be2   = (const float*)d_in[14];
    const float* W_out = (const float*)d_in[15];
    const float* b_out = (const float*)d_in[16];
    (void)in_sizes; (void)n_in; (void)out_size; (void)ws_size;

    const size_t SZ = (size_t)NB * NTOK * E;
    float*  H   = (float*)d_ws;
    ushort* Hb  = (ushort*)(H + SZ);
    ushort* Qb  = Hb + SZ;
    ushort* Kb  = Qb + SZ;
    ushort* VTg = Kb + SZ;                          // [b][e][tok]
    ushort* WT  = VTg + SZ;                         // 60 x 64K bf16 transposed weights

    k_wprep<<<dim3(NLAYER * 5), dim3(256), 0, stream>>>(Wq, Wk, Wv, W1, W2, WT);
    k_embed<<<dim3(2048), dim3(256), 0, stream>>>(xs, ys, W_in, b_in, H, Hb);
    for (int i = 0; i < NLAYER; ++i) {
        const size_t vo = (size_t)i * E;
        const ushort* WqT = WT + ((size_t)(i * 5 + 0) << 16);
        const ushort* WkT = WT + ((size_t)(i * 5 + 1) << 16);
        const ushort* WvT = WT + ((size_t)(i * 5 + 2) << 16);
        const ushort* W1T = WT + ((size_t)(i * 5 + 3) << 16);
        const ushort* W2T = WT + ((size_t)(i * 5 + 4) << 16);
        k_qkv<<<dim3(512), dim3(256), 0, stream>>>(Hb, WqT, WkT, WvT, Qb, Kb, VTg);
        k_attn<<<dim3(256), dim3(512), 0, stream>>>(Qb, Kb, VTg, H, Hb, g1 + vo, be1 + vo);
        k_mlp<<<dim3(512), dim3(256), 0, stream>>>(Hb, H, Hb, W1T, b1 + vo, W2T, b2 + vo,
                                                   g2 + vo, be2 + vo);
    }
    k_readout<<<dim3((NB * NTOK) / 4), dim3(256), 0, stream>>>(H, W_out, b_out, (float*)d_out);
}